// Round 2
// baseline (498.598 us; speedup 1.0000x reference)
//
#include <hip/hip_runtime.h>
#include <hip/hip_bf16.h>
#include <stdint.h>

typedef __attribute__((ext_vector_type(8))) short s8v;
typedef __attribute__((ext_vector_type(4))) float f4v;

#define T_TOT 8
#define HW 64
#define NSP 32768   // T*H*W
#define K_TOT 1024
#define M_TOT 1024

__device__ __forceinline__ unsigned short f2bf(float f) {
  unsigned int u = __float_as_uint(f);
  u += 0x7FFF + ((u >> 16) & 1);   // round-to-nearest-even
  return (unsigned short)(u >> 16);
}

// ---------------------------------------------------------------------------
// Kernel 1: depthwise 3x3x3 conv (shared kernel), bf16 cast, transpose to
// Yt[n][c]  (n = t*4096 + h*64 + w).
// Block: 32 channels x 2 h-rows x 64 w at fixed t.  256 threads:
//   cl = tid>>3 (channel 0..31), wc = tid&7 (w-chunk of 8).
// Thread computes 2h x 8w outputs; all 48 global loads are independent
// (2 float4 + 2 edge scalars per input row, 12 rows) -> bulk issue, no
// shuffles, latency hidden by occupancy.
// ---------------------------------------------------------------------------
__global__ __launch_bounds__(256) void dw_t_kernel(const float* __restrict__ X,
                                                   const float* __restrict__ DW,
                                                   unsigned short* __restrict__ Yt) {
  __shared__ unsigned short tile[128][34];   // [n_local][c_local], pad 32->34
  const int tid = threadIdx.x;
  const int cl  = tid >> 3;                  // 0..31
  const int wc  = tid & 7;                   // 0..7
  const int w0  = wc * 8;
  const int c0  = blockIdx.x * 32;
  const int t   = blockIdx.y;
  const int h0  = blockIdx.z * 2;

  float kw[27];
#pragma unroll
  for (int j = 0; j < 27; ++j) kw[j] = DW[j];   // uniform -> s_loads

  const int c = c0 + cl;
  const float* Xc = X + (size_t)c * NSP;

  float acc[2][8];
#pragma unroll
  for (int ho = 0; ho < 2; ++ho)
#pragma unroll
    for (int j = 0; j < 8; ++j) acc[ho][j] = 0.f;

#pragma unroll
  for (int tt = 0; tt < 3; ++tt) {
    const int ta = t + tt - 1;
    const bool tok = (ta >= 0) && (ta < T_TOT);
#pragma unroll
    for (int rr = 0; rr < 4; ++rr) {           // input row hh = h0-1+rr
      const int hh = h0 - 1 + rr;
      const bool ok = tok && (hh >= 0) && (hh < 64);
      const float* row = Xc + (ta * 64 + hh) * 64;
      const float4 z4 = {0.f, 0.f, 0.f, 0.f};
      float4 cA = ok ? *(const float4*)(row + w0)     : z4;
      float4 cB = ok ? *(const float4*)(row + w0 + 4) : z4;
      float  xl = (ok && w0 > 0)      ? row[w0 - 1] : 0.f;
      float  xr = (ok && w0 + 8 < 64) ? row[w0 + 8] : 0.f;
      float x[10];
      x[0] = xl;
      x[1] = cA.x; x[2] = cA.y; x[3] = cA.z; x[4] = cA.w;
      x[5] = cB.x; x[6] = cB.y; x[7] = cB.z; x[8] = cB.w;
      x[9] = xr;
#pragma unroll
      for (int ho = 0; ho < 2; ++ho) {
        const int kh = rr - ho;                // compile-time after unroll
        if (kh >= 0 && kh < 3) {
          const float k0 = kw[(tt * 3 + kh) * 3 + 0];
          const float k1 = kw[(tt * 3 + kh) * 3 + 1];
          const float k2 = kw[(tt * 3 + kh) * 3 + 2];
#pragma unroll
          for (int j = 0; j < 8; ++j)
            acc[ho][j] += k0 * x[j] + k1 * x[j + 1] + k2 * x[j + 2];
        }
      }
    }
  }

#pragma unroll
  for (int ho = 0; ho < 2; ++ho)
#pragma unroll
    for (int j = 0; j < 8; ++j)
      tile[ho * 64 + w0 + j][cl] = f2bf(acc[ho][j]);
  __syncthreads();

  // coalesced transposed store: 4 lanes cover one n (32 c = 64B)
  const int nbase = t * 4096 + h0 * 64;
#pragma unroll
  for (int i = 0; i < 2; ++i) {
    const int nl = i * 64 + (tid >> 2);
    const int cd = (tid & 3);
    const unsigned int* src = (const unsigned int*)&tile[nl][cd * 8];
    uint4 v;
    v.x = src[0]; v.y = src[1]; v.z = src[2]; v.w = src[3];
    *(uint4*)&Yt[(size_t)(nbase + nl) * 1024 + c0 + cd * 8] = v;
  }
}

// ---------------------------------------------------------------------------
// Kernel 2: pointwise weight fp32 -> bf16, [1024][1024]
// ---------------------------------------------------------------------------
__global__ __launch_bounds__(256) void castw_kernel(const float* __restrict__ Wf,
                                                    unsigned short* __restrict__ Wb) {
  const int i = (blockIdx.x * 256 + threadIdx.x) * 4;
  float4 v = *(const float4*)&Wf[i];
  ushort4 o;
  o.x = f2bf(v.x); o.y = f2bf(v.y); o.z = f2bf(v.z); o.w = f2bf(v.w);
  *(ushort4*)&Wb[i] = o;
}

// ---------------------------------------------------------------------------
// Kernel 3: C[M][N] = A[M][K] * Bt[N][K]^T   (m97-style 128x128 tile, BK=32)
// A = Wb (bf16), Bt = Yt (bf16), C = out (f32).   (unchanged this round)
// ---------------------------------------------------------------------------
__device__ __forceinline__ void gload_lds16(const void* g, void* lds) {
  __builtin_amdgcn_global_load_lds(
      (const __attribute__((address_space(1))) void*)(uintptr_t)g,
      (__attribute__((address_space(3))) void*)(uintptr_t)lds, 16, 0, 0);
}

__global__ __launch_bounds__(256) void gemm_kernel(const unsigned short* __restrict__ A,
                                                   const unsigned short* __restrict__ B,
                                                   float* __restrict__ C) {
  __shared__ unsigned short As[128][32];   // 8 KB
  __shared__ unsigned short Bs[128][32];   // 8 KB
  const int tid  = threadIdx.x;
  const int lane = tid & 63;
  const int wv   = tid >> 6;
  const int wr   = wv >> 1, wc = wv & 1;
  const int bn   = blockIdx.x, bm = blockIdx.y;

  f4v acc[4][4];
#pragma unroll
  for (int i = 0; i < 4; ++i)
#pragma unroll
    for (int j = 0; j < 4; ++j) acc[i][j] = (f4v){0.f, 0.f, 0.f, 0.f};

  const int r  = tid >> 2;           // tile row 0..63 (inst0) / +64 (inst1)
  const int kb = (tid & 3) * 8;      // k element offset within BK
  const unsigned short* ga0 = A + (size_t)(bm * 128 + r) * K_TOT + kb;
  const unsigned short* gb0 = B + (size_t)(bn * 128 + r) * K_TOT + kb;
  char* ldsA = (char*)(&As[0][0]) + wv * 1024;   // lane data lands at +lane*16 => linear [row][k]
  char* ldsB = (char*)(&Bs[0][0]) + wv * 1024;

  for (int kt = 0; kt < K_TOT; kt += 32) {
    __syncthreads();                 // previous compute done before overwrite
    gload_lds16(ga0 + kt,               ldsA);
    gload_lds16(ga0 + 64 * K_TOT + kt,  ldsA + 4096);
    gload_lds16(gb0 + kt,               ldsB);
    gload_lds16(gb0 + 64 * K_TOT + kt,  ldsB + 4096);
    __syncthreads();                 // compiler drains vmcnt(0) before barrier

    s8v a[4], b[4];
#pragma unroll
    for (int mf = 0; mf < 4; ++mf)
      a[mf] = *(const s8v*)&As[wr * 64 + mf * 16 + (lane & 15)][(lane >> 4) * 8];
#pragma unroll
    for (int nf = 0; nf < 4; ++nf)
      b[nf] = *(const s8v*)&Bs[wc * 64 + nf * 16 + (lane & 15)][(lane >> 4) * 8];
#pragma unroll
    for (int mf = 0; mf < 4; ++mf)
#pragma unroll
      for (int nf = 0; nf < 4; ++nf)
        acc[mf][nf] = __builtin_amdgcn_mfma_f32_16x16x32_bf16(a[mf], b[nf], acc[mf][nf], 0, 0, 0);
  }

  // epilogue: D[row=(lane>>4)*4+j][col=lane&15]
  const int rowq = (lane >> 4) * 4;
  const int colq = lane & 15;
#pragma unroll
  for (int mf = 0; mf < 4; ++mf) {
    const int row0 = bm * 128 + wr * 64 + mf * 16 + rowq;
#pragma unroll
    for (int nf = 0; nf < 4; ++nf) {
      const int col = bn * 128 + wc * 64 + nf * 16 + colq;
      float* cp = C + (size_t)row0 * NSP + col;
#pragma unroll
      for (int j = 0; j < 4; ++j) cp[(size_t)j * NSP] = acc[mf][nf][j];
    }
  }
}

// ---------------------------------------------------------------------------
extern "C" void kernel_launch(void* const* d_in, const int* in_sizes, int n_in,
                              void* d_out, int out_size, void* d_ws, size_t ws_size,
                              hipStream_t stream) {
  const float* feat = (const float*)d_in[0];
  const float* dw   = (const float*)d_in[1];
  const float* pw   = (const float*)d_in[2];
  float* out = (float*)d_out;

  unsigned short* Yt = (unsigned short*)d_ws;                 // [32768][1024] bf16, 64 MiB
  unsigned short* Wb = Yt + (size_t)NSP * 1024;               // [1024][1024] bf16, 2 MiB

  dw_t_kernel<<<dim3(32, 8, 32), dim3(256), 0, stream>>>(feat, dw, Yt);
  castw_kernel<<<dim3(1024), dim3(256), 0, stream>>>(pw, Wb);
  gemm_kernel<<<dim3(256, 8), dim3(256), 0, stream>>>(Wb, Yt, out);
}

// Round 3
// 216.628 us; speedup vs baseline: 2.3016x; 2.3016x over previous
//
#include <hip/hip_runtime.h>
#include <hip/hip_bf16.h>
#include <stdint.h>

typedef __attribute__((ext_vector_type(8))) short s8v;
typedef __attribute__((ext_vector_type(4))) float f4v;

#define T_TOT 8
#define NSP 32768   // T*H*W
#define K_TOT 1024
#define M_TOT 1024

__device__ __forceinline__ unsigned short f2bf(float f) {
  unsigned int u = __float_as_uint(f);
  u += 0x7FFF + ((u >> 16) & 1);   // round-to-nearest-even
  return (unsigned short)(u >> 16);
}

// ---------------------------------------------------------------------------
// Kernel 1 (v3): depthwise 3x3x3, shared kernel. Block = (h-band of 16, c).
// Stage X[c][t=0..8][h0-1..h0+16][w] fp32 into LDS with perfectly coalesced
// 1KB wave loads, then compute all 8 t-outputs from LDS (imm-offset b32
// reads, stride-1 lanes = conflict-free). Output Yn[c][n] bf16, n-major.
// ---------------------------------------------------------------------------
__global__ __launch_bounds__(256) void dw_kernel(const float* __restrict__ X,
                                                 const float* __restrict__ DW,
                                                 unsigned short* __restrict__ Yn) {
  __shared__ float xin[8 * 18 * 64];         // 36 KB  [t][hr][w], hr = h-(h0-1)
  const int tid = threadIdx.x;
  const int hb  = blockIdx.x;                // 0..3
  const int c   = blockIdx.y;                // 0..1023
  const int h0  = hb * 16;

  float kw[27];
#pragma unroll
  for (int j = 0; j < 27; ++j) kw[j] = DW[j];   // uniform -> scalar loads

  const float* Xc = X + (size_t)c * NSP;

  // ---- stage: 2304 float4, 9 per thread, all unconditional & contiguous ----
#pragma unroll
  for (int i = 0; i < 9; ++i) {
    const int f  = tid + i * 256;            // float4 index 0..2303
    const int r  = f >> 4;                   // lds row 0..143 (= t*18+hr)
    const int wq = (f & 15) * 4;
    const int t  = r / 18;
    const int hr = r - t * 18;
    const int hg = h0 - 1 + hr;              // global h, may be -1 or 64
    const int hc = min(max(hg, 0), 63);      // clamp ADDRESS (stay in-buffer)
    float4 v = *(const float4*)(Xc + (t * 64 + hc) * 64 + wq);
    if (hg != hc) v = (float4){0.f, 0.f, 0.f, 0.f};   // zero VALUE when OOB
    *(float4*)&xin[r * 64 + wq] = v;
  }
  __syncthreads();

  // ---- compute: thread = (w = tid&63, hq = tid>>6 -> rows hq*4..hq*4+3) ----
  const int w  = tid & 63;
  const int hq = tid >> 6;
  const int wl = (w == 0)  ? w : w - 1;      // clamped addr, value fixed below
  const int wr = (w == 63) ? w : w + 1;
  const float* bC = &xin[(hq * 4) * 64 + w];
  const float* bL = &xin[(hq * 4) * 64 + wl];
  const float* bR = &xin[(hq * 4) * 64 + wr];
  unsigned short* Yb = Yn + (size_t)c * NSP + (h0 + hq * 4) * 64 + w;

  float a0[4], a1[4], a2[4];                 // tout = tp-1, tp, tp+1
#pragma unroll
  for (int j = 0; j < 4; ++j) { a0[j] = 0.f; a1[j] = 0.f; a2[j] = 0.f; }

#pragma unroll
  for (int tp = 0; tp < 8; ++tp) {           // input plane
    float v[6][3];
#pragma unroll
    for (int rr = 0; rr < 6; ++rr) {         // lds row = hq*4 + rr (<=17 ok)
      const int off = (tp * 18 + rr) * 64;   // pure imm offsets from bases
      float xc = bC[off];
      float xl = bL[off];
      float xr = bR[off];
      if (w == 0)  xl = 0.f;
      if (w == 63) xr = 0.f;
      v[rr][0] = xl; v[rr][1] = xc; v[rr][2] = xr;
    }
#pragma unroll
    for (int j = 0; j < 4; ++j)
#pragma unroll
      for (int kh = 0; kh < 3; ++kh)
#pragma unroll
        for (int kd = 0; kd < 3; ++kd) {
          const float xv = v[j + kh][kd];
          if (tp >= 1) a0[j] += kw[(2 * 3 + kh) * 3 + kd] * xv;  // tt=2
          a1[j] += kw[(1 * 3 + kh) * 3 + kd] * xv;               // tt=1
          if (tp <= 6) a2[j] += kw[(0 * 3 + kh) * 3 + kd] * xv;  // tt=0
        }
    if (tp >= 1) {                           // tout = tp-1 complete -> store
      unsigned short* yp = Yb + (size_t)(tp - 1) * 4096;
#pragma unroll
      for (int j = 0; j < 4; ++j) yp[j * 64] = f2bf(a0[j]);
    }
#pragma unroll
    for (int j = 0; j < 4; ++j) { a0[j] = a1[j]; a1[j] = a2[j]; a2[j] = 0.f; }
  }
  {                                          // tout = 7
    unsigned short* yp = Yb + (size_t)7 * 4096;
#pragma unroll
    for (int j = 0; j < 4; ++j) yp[j * 64] = f2bf(a0[j]);
  }
}

// ---------------------------------------------------------------------------
// Kernel 2: pointwise weight fp32 -> bf16, [1024][1024]
// ---------------------------------------------------------------------------
__global__ __launch_bounds__(256) void castw_kernel(const float* __restrict__ Wf,
                                                    unsigned short* __restrict__ Wb) {
  const int i = (blockIdx.x * 256 + threadIdx.x) * 4;
  float4 v = *(const float4*)&Wf[i];
  ushort4 o;
  o.x = f2bf(v.x); o.y = f2bf(v.y); o.z = f2bf(v.z); o.w = f2bf(v.w);
  *(ushort4*)&Wb[i] = o;
}

// ---------------------------------------------------------------------------
// Kernel 3: C[M][N] = A[M][K] * B[K][N]. A = Wb [o][c] bf16 (gload_lds path,
// unchanged). B = Yn [k][n] bf16, reg-staged with 4x4 u16 register transpose
// into Bs[n][kpad=40] so MFMA B-frag reads stay ds_read_b128, 16B-aligned.
// ---------------------------------------------------------------------------
__device__ __forceinline__ void gload_lds16(const void* g, void* lds) {
  __builtin_amdgcn_global_load_lds(
      (const __attribute__((address_space(1))) void*)(uintptr_t)g,
      (__attribute__((address_space(3))) void*)(uintptr_t)lds, 16, 0, 0);
}

__global__ __launch_bounds__(256) void gemm_kernel(const unsigned short* __restrict__ A,
                                                   const unsigned short* __restrict__ B,
                                                   float* __restrict__ C) {
  __shared__ unsigned short As[128][32];   // 8 KB, [m][k]
  __shared__ unsigned short Bs[128][40];   // 10 KB, [n][k] pad->40 (16B align)
  const int tid  = threadIdx.x;
  const int lane = tid & 63;
  const int wv   = tid >> 6;
  const int wr   = wv >> 1, wc = wv & 1;
  const int bn   = blockIdx.x, bm = blockIdx.y;
  const int n0   = bn * 128;

  f4v acc[4][4];
#pragma unroll
  for (int i = 0; i < 4; ++i)
#pragma unroll
    for (int j = 0; j < 4; ++j) acc[i][j] = (f4v){0.f, 0.f, 0.f, 0.f};

  // A staging (unchanged): global_load_lds width 16
  const int r  = tid >> 2;
  const int kb = (tid & 3) * 8;
  const unsigned short* ga0 = A + (size_t)(bm * 128 + r) * K_TOT + kb;
  char* ldsA = (char*)(&As[0][0]) + wv * 1024;

  // B staging: thread = (nq = tid>>3 -> 4 n, kq = tid&7 -> 4 k)
  const int nq4 = (tid >> 3) * 4;
  const int kq4 = (tid & 7) * 4;

  for (int kt = 0; kt < K_TOT; kt += 32) {
    __syncthreads();                 // previous compute done before overwrite
    gload_lds16(ga0 + kt,               ldsA);
    gload_lds16(ga0 + 64 * K_TOT + kt,  ldsA + 4096);

    const unsigned short* gB = B + (size_t)(kt + kq4) * NSP + n0 + nq4;
    uint2 L0 = *(const uint2*)(gB);
    uint2 L1 = *(const uint2*)(gB + NSP);
    uint2 L2 = *(const uint2*)(gB + 2 * NSP);
    uint2 L3 = *(const uint2*)(gB + 3 * NSP);
    // 4x4 u16 transpose: W_e = { B[k0][n+e], B[k1][n+e], B[k2][n+e], B[k3][n+e] }
    uint2 W0, W1, W2, W3;
    W0.x = (L0.x & 0xFFFFu) | (L1.x << 16);
    W0.y = (L2.x & 0xFFFFu) | (L3.x << 16);
    W1.x = (L0.x >> 16) | (L1.x & 0xFFFF0000u);
    W1.y = (L2.x >> 16) | (L3.x & 0xFFFF0000u);
    W2.x = (L0.y & 0xFFFFu) | (L1.y << 16);
    W2.y = (L2.y & 0xFFFFu) | (L3.y << 16);
    W3.x = (L0.y >> 16) | (L1.y & 0xFFFF0000u);
    W3.y = (L2.y >> 16) | (L3.y & 0xFFFF0000u);
    *(uint2*)&Bs[nq4 + 0][kq4] = W0;
    *(uint2*)&Bs[nq4 + 1][kq4] = W1;
    *(uint2*)&Bs[nq4 + 2][kq4] = W2;
    *(uint2*)&Bs[nq4 + 3][kq4] = W3;
    __syncthreads();

    s8v a[4], b[4];
#pragma unroll
    for (int mf = 0; mf < 4; ++mf)
      a[mf] = *(const s8v*)&As[wr * 64 + mf * 16 + (lane & 15)][(lane >> 4) * 8];
#pragma unroll
    for (int nf = 0; nf < 4; ++nf)
      b[nf] = *(const s8v*)&Bs[wc * 64 + nf * 16 + (lane & 15)][(lane >> 4) * 8];
#pragma unroll
    for (int mf = 0; mf < 4; ++mf)
#pragma unroll
      for (int nf = 0; nf < 4; ++nf)
        acc[mf][nf] = __builtin_amdgcn_mfma_f32_16x16x32_bf16(a[mf], b[nf], acc[mf][nf], 0, 0, 0);
  }

  // epilogue: D[row=(lane>>4)*4+j][col=lane&15]
  const int rowq = (lane >> 4) * 4;
  const int colq = lane & 15;
#pragma unroll
  for (int mf = 0; mf < 4; ++mf) {
    const int row0 = bm * 128 + wr * 64 + mf * 16 + rowq;
#pragma unroll
    for (int nf = 0; nf < 4; ++nf) {
      const int col = n0 + wc * 64 + nf * 16 + colq;
      float* cp = C + (size_t)row0 * NSP + col;
#pragma unroll
      for (int j = 0; j < 4; ++j) cp[(size_t)j * NSP] = acc[mf][nf][j];
    }
  }
}

// ---------------------------------------------------------------------------
extern "C" void kernel_launch(void* const* d_in, const int* in_sizes, int n_in,
                              void* d_out, int out_size, void* d_ws, size_t ws_size,
                              hipStream_t stream) {
  const float* feat = (const float*)d_in[0];
  const float* dw   = (const float*)d_in[1];
  const float* pw   = (const float*)d_in[2];
  float* out = (float*)d_out;

  unsigned short* Yn = (unsigned short*)d_ws;                 // [1024][32768] bf16, 64 MiB
  unsigned short* Wb = Yn + (size_t)K_TOT * NSP;              // [1024][1024] bf16, 2 MiB

  dw_kernel<<<dim3(4, 1024), dim3(256), 0, stream>>>(feat, dw, Yn);
  castw_kernel<<<dim3(1024), dim3(256), 0, stream>>>(pw, Wb);
  gemm_kernel<<<dim3(256, 8), dim3(256), 0, stream>>>(Wb, Yn, out);
}

// Round 4
// 189.463 us; speedup vs baseline: 2.6316x; 1.1434x over previous
//
#include <hip/hip_runtime.h>
#include <hip/hip_bf16.h>
#include <stdint.h>

typedef __attribute__((ext_vector_type(8))) short s8v;
typedef __attribute__((ext_vector_type(4))) float f4v;

#define T_TOT 8
#define NSP 32768   // T*H*W
#define K_TOT 1024
#define M_TOT 1024

__device__ __forceinline__ unsigned short f2bf(float f) {
  unsigned int u = __float_as_uint(f);
  u += 0x7FFF + ((u >> 16) & 1);   // round-to-nearest-even
  return (unsigned short)(u >> 16);
}

// ---------------------------------------------------------------------------
// Kernel 1 (v3, unchanged): depthwise 3x3x3, shared kernel. Block=(h16, c).
// Stages X[c] slab in LDS with 1KB coalesced wave loads; computes 8 t-planes
// from LDS; writes Yn[c][n] bf16 with 128B coalesced rows.  ~35us measured.
// ---------------------------------------------------------------------------
__global__ __launch_bounds__(256) void dw_kernel(const float* __restrict__ X,
                                                 const float* __restrict__ DW,
                                                 unsigned short* __restrict__ Yn) {
  __shared__ float xin[8 * 18 * 64];         // 36 KB  [t][hr][w]
  const int tid = threadIdx.x;
  const int hb  = blockIdx.x;                // 0..3
  const int c   = blockIdx.y;                // 0..1023
  const int h0  = hb * 16;

  float kw[27];
#pragma unroll
  for (int j = 0; j < 27; ++j) kw[j] = DW[j];

  const float* Xc = X + (size_t)c * NSP;

#pragma unroll
  for (int i = 0; i < 9; ++i) {
    const int f  = tid + i * 256;
    const int r  = f >> 4;
    const int wq = (f & 15) * 4;
    const int t  = r / 18;
    const int hr = r - t * 18;
    const int hg = h0 - 1 + hr;
    const int hc = min(max(hg, 0), 63);
    float4 v = *(const float4*)(Xc + (t * 64 + hc) * 64 + wq);
    if (hg != hc) v = (float4){0.f, 0.f, 0.f, 0.f};
    *(float4*)&xin[r * 64 + wq] = v;
  }
  __syncthreads();

  const int w  = tid & 63;
  const int hq = tid >> 6;
  const int wl = (w == 0)  ? w : w - 1;
  const int wr = (w == 63) ? w : w + 1;
  const float* bC = &xin[(hq * 4) * 64 + w];
  const float* bL = &xin[(hq * 4) * 64 + wl];
  const float* bR = &xin[(hq * 4) * 64 + wr];
  unsigned short* Yb = Yn + (size_t)c * NSP + (h0 + hq * 4) * 64 + w;

  float a0[4], a1[4], a2[4];
#pragma unroll
  for (int j = 0; j < 4; ++j) { a0[j] = 0.f; a1[j] = 0.f; a2[j] = 0.f; }

#pragma unroll
  for (int tp = 0; tp < 8; ++tp) {
    float v[6][3];
#pragma unroll
    for (int rr = 0; rr < 6; ++rr) {
      const int off = (tp * 18 + rr) * 64;
      float xc = bC[off];
      float xl = bL[off];
      float xr = bR[off];
      if (w == 0)  xl = 0.f;
      if (w == 63) xr = 0.f;
      v[rr][0] = xl; v[rr][1] = xc; v[rr][2] = xr;
    }
#pragma unroll
    for (int j = 0; j < 4; ++j)
#pragma unroll
      for (int kh = 0; kh < 3; ++kh)
#pragma unroll
        for (int kd = 0; kd < 3; ++kd) {
          const float xv = v[j + kh][kd];
          if (tp >= 1) a0[j] += kw[(2 * 3 + kh) * 3 + kd] * xv;
          a1[j] += kw[(1 * 3 + kh) * 3 + kd] * xv;
          if (tp <= 6) a2[j] += kw[(0 * 3 + kh) * 3 + kd] * xv;
        }
    if (tp >= 1) {
      unsigned short* yp = Yb + (size_t)(tp - 1) * 4096;
#pragma unroll
      for (int j = 0; j < 4; ++j) yp[j * 64] = f2bf(a0[j]);
    }
#pragma unroll
    for (int j = 0; j < 4; ++j) { a0[j] = a1[j]; a1[j] = a2[j]; a2[j] = 0.f; }
  }
  {
    unsigned short* yp = Yb + (size_t)7 * 4096;
#pragma unroll
    for (int j = 0; j < 4; ++j) yp[j * 64] = f2bf(a0[j]);
  }
}

// ---------------------------------------------------------------------------
// Kernel 1b (new): transpose Yn[1024 c][32768 n] -> Yt[32768 n][1024 c].
// 64x64 bf16 tiles via LDS (pitch 68 u16): loads 128B full lines, b64 LDS
// writes ~2-way, u16 gather reads conflict-free (banks cq*8+j*2+n/2),
// stores 64B-grouped uint4.  Pure BW: 128MB -> ~22us.
// ---------------------------------------------------------------------------
__global__ __launch_bounds__(256) void tr_kernel(const unsigned short* __restrict__ Yn,
                                                 unsigned short* __restrict__ Yt) {
  __shared__ unsigned short tb[64][68];      // 8.5 KB, pitch 136B (8B aligned)
  const int tid = threadIdx.x;
  const int n0  = blockIdx.x * 64;
  const int c0  = blockIdx.y * 64;

#pragma unroll
  for (int i = 0; i < 2; ++i) {
    const int cl = (tid >> 3) + i * 32;      // 0..63
    const int n8 = (tid & 7) * 8;
    const uint4 v = *(const uint4*)(Yn + (size_t)(c0 + cl) * NSP + n0 + n8);
    uint2 lo; lo.x = v.x; lo.y = v.y;
    uint2 hi; hi.x = v.z; hi.y = v.w;
    *(uint2*)&tb[cl][n8]     = lo;
    *(uint2*)&tb[cl][n8 + 4] = hi;
  }
  __syncthreads();

  const int nl = tid >> 2;                   // 0..63
  const int cq = tid & 3;
#pragma unroll
  for (int i = 0; i < 2; ++i) {
    const int c8 = cq * 8 + i * 32;          // 0..56
    unsigned int p[4];
#pragma unroll
    for (int j = 0; j < 4; ++j) {
      const unsigned int a = tb[c8 + 2 * j][nl];
      const unsigned int b = tb[c8 + 2 * j + 1][nl];
      p[j] = a | (b << 16);
    }
    uint4 o; o.x = p[0]; o.y = p[1]; o.z = p[2]; o.w = p[3];
    *(uint4*)(Yt + (size_t)(n0 + nl) * 1024 + c0 + c8) = o;
  }
}

// ---------------------------------------------------------------------------
// Kernel 2: pointwise weight fp32 -> bf16, [1024][1024]
// ---------------------------------------------------------------------------
__global__ __launch_bounds__(256) void castw_kernel(const float* __restrict__ Wf,
                                                    unsigned short* __restrict__ Wb) {
  const int i = (blockIdx.x * 256 + threadIdx.x) * 4;
  float4 v = *(const float4*)&Wf[i];
  ushort4 o;
  o.x = f2bf(v.x); o.y = f2bf(v.y); o.z = f2bf(v.z); o.w = f2bf(v.w);
  *(ushort4*)&Wb[i] = o;
}

// ---------------------------------------------------------------------------
// Kernel 3 (round-1 verbatim, measured ~95us): C[M][N] = A[M][K]*Bt[N][K]^T,
// m97 structure: 128x128 tile, BK=32, dual global_load_lds width-16.
// ---------------------------------------------------------------------------
__device__ __forceinline__ void gload_lds16(const void* g, void* lds) {
  __builtin_amdgcn_global_load_lds(
      (const __attribute__((address_space(1))) void*)(uintptr_t)g,
      (__attribute__((address_space(3))) void*)(uintptr_t)lds, 16, 0, 0);
}

__global__ __launch_bounds__(256) void gemm_kernel(const unsigned short* __restrict__ A,
                                                   const unsigned short* __restrict__ B,
                                                   float* __restrict__ C) {
  __shared__ unsigned short As[128][32];   // 8 KB
  __shared__ unsigned short Bs[128][32];   // 8 KB
  const int tid  = threadIdx.x;
  const int lane = tid & 63;
  const int wv   = tid >> 6;
  const int wr   = wv >> 1, wc = wv & 1;
  const int bn   = blockIdx.x, bm = blockIdx.y;

  f4v acc[4][4];
#pragma unroll
  for (int i = 0; i < 4; ++i)
#pragma unroll
    for (int j = 0; j < 4; ++j) acc[i][j] = (f4v){0.f, 0.f, 0.f, 0.f};

  const int r  = tid >> 2;
  const int kb = (tid & 3) * 8;
  const unsigned short* ga0 = A + (size_t)(bm * 128 + r) * K_TOT + kb;
  const unsigned short* gb0 = B + (size_t)(bn * 128 + r) * K_TOT + kb;
  char* ldsA = (char*)(&As[0][0]) + wv * 1024;
  char* ldsB = (char*)(&Bs[0][0]) + wv * 1024;

  for (int kt = 0; kt < K_TOT; kt += 32) {
    __syncthreads();
    gload_lds16(ga0 + kt,               ldsA);
    gload_lds16(ga0 + 64 * K_TOT + kt,  ldsA + 4096);
    gload_lds16(gb0 + kt,               ldsB);
    gload_lds16(gb0 + 64 * K_TOT + kt,  ldsB + 4096);
    __syncthreads();

    s8v a[4], b[4];
#pragma unroll
    for (int mf = 0; mf < 4; ++mf)
      a[mf] = *(const s8v*)&As[wr * 64 + mf * 16 + (lane & 15)][(lane >> 4) * 8];
#pragma unroll
    for (int nf = 0; nf < 4; ++nf)
      b[nf] = *(const s8v*)&Bs[wc * 64 + nf * 16 + (lane & 15)][(lane >> 4) * 8];
#pragma unroll
    for (int mf = 0; mf < 4; ++mf)
#pragma unroll
      for (int nf = 0; nf < 4; ++nf)
        acc[mf][nf] = __builtin_amdgcn_mfma_f32_16x16x32_bf16(a[mf], b[nf], acc[mf][nf], 0, 0, 0);
  }

  const int rowq = (lane >> 4) * 4;
  const int colq = lane & 15;
#pragma unroll
  for (int mf = 0; mf < 4; ++mf) {
    const int row0 = bm * 128 + wr * 64 + mf * 16 + rowq;
#pragma unroll
    for (int nf = 0; nf < 4; ++nf) {
      const int col = bn * 128 + wc * 64 + nf * 16 + colq;
      float* cp = C + (size_t)row0 * NSP + col;
#pragma unroll
      for (int j = 0; j < 4; ++j) cp[(size_t)j * NSP] = acc[mf][nf][j];
    }
  }
}

// ---------------------------------------------------------------------------
// Fallback GEMM (round-3 verbatim): consumes Yn[k][n] directly (reg-staged
// B transpose).  Used only if ws_size can't fit both Yn and Yt.
// ---------------------------------------------------------------------------
__global__ __launch_bounds__(256) void gemm_nmajor_kernel(const unsigned short* __restrict__ A,
                                                          const unsigned short* __restrict__ B,
                                                          float* __restrict__ C) {
  __shared__ unsigned short As[128][32];
  __shared__ unsigned short Bs[128][40];
  const int tid  = threadIdx.x;
  const int lane = tid & 63;
  const int wv   = tid >> 6;
  const int wr   = wv >> 1, wc = wv & 1;
  const int bn   = blockIdx.x, bm = blockIdx.y;
  const int n0   = bn * 128;

  f4v acc[4][4];
#pragma unroll
  for (int i = 0; i < 4; ++i)
#pragma unroll
    for (int j = 0; j < 4; ++j) acc[i][j] = (f4v){0.f, 0.f, 0.f, 0.f};

  const int r  = tid >> 2;
  const int kb = (tid & 3) * 8;
  const unsigned short* ga0 = A + (size_t)(bm * 128 + r) * K_TOT + kb;
  char* ldsA = (char*)(&As[0][0]) + wv * 1024;
  const int nq4 = (tid >> 3) * 4;
  const int kq4 = (tid & 7) * 4;

  for (int kt = 0; kt < K_TOT; kt += 32) {
    __syncthreads();
    gload_lds16(ga0 + kt,               ldsA);
    gload_lds16(ga0 + 64 * K_TOT + kt,  ldsA + 4096);

    const unsigned short* gB = B + (size_t)(kt + kq4) * NSP + n0 + nq4;
    uint2 L0 = *(const uint2*)(gB);
    uint2 L1 = *(const uint2*)(gB + NSP);
    uint2 L2 = *(const uint2*)(gB + 2 * NSP);
    uint2 L3 = *(const uint2*)(gB + 3 * NSP);
    uint2 W0, W1, W2, W3;
    W0.x = (L0.x & 0xFFFFu) | (L1.x << 16);
    W0.y = (L2.x & 0xFFFFu) | (L3.x << 16);
    W1.x = (L0.x >> 16) | (L1.x & 0xFFFF0000u);
    W1.y = (L2.x >> 16) | (L3.x & 0xFFFF0000u);
    W2.x = (L0.y & 0xFFFFu) | (L1.y << 16);
    W2.y = (L2.y & 0xFFFFu) | (L3.y << 16);
    W3.x = (L0.y >> 16) | (L1.y & 0xFFFF0000u);
    W3.y = (L2.y >> 16) | (L3.y & 0xFFFF0000u);
    *(uint2*)&Bs[nq4 + 0][kq4] = W0;
    *(uint2*)&Bs[nq4 + 1][kq4] = W1;
    *(uint2*)&Bs[nq4 + 2][kq4] = W2;
    *(uint2*)&Bs[nq4 + 3][kq4] = W3;
    __syncthreads();

    s8v a[4], b[4];
#pragma unroll
    for (int mf = 0; mf < 4; ++mf)
      a[mf] = *(const s8v*)&As[wr * 64 + mf * 16 + (lane & 15)][(lane >> 4) * 8];
#pragma unroll
    for (int nf = 0; nf < 4; ++nf)
      b[nf] = *(const s8v*)&Bs[wc * 64 + nf * 16 + (lane & 15)][(lane >> 4) * 8];
#pragma unroll
    for (int mf = 0; mf < 4; ++mf)
#pragma unroll
      for (int nf = 0; nf < 4; ++nf)
        acc[mf][nf] = __builtin_amdgcn_mfma_f32_16x16x32_bf16(a[mf], b[nf], acc[mf][nf], 0, 0, 0);
  }

  const int rowq = (lane >> 4) * 4;
  const int colq = lane & 15;
#pragma unroll
  for (int mf = 0; mf < 4; ++mf) {
    const int row0 = bm * 128 + wr * 64 + mf * 16 + rowq;
#pragma unroll
    for (int nf = 0; nf < 4; ++nf) {
      const int col = n0 + wc * 64 + nf * 16 + colq;
      float* cp = C + (size_t)row0 * NSP + col;
#pragma unroll
      for (int j = 0; j < 4; ++j) cp[(size_t)j * NSP] = acc[mf][nf][j];
    }
  }
}

// ---------------------------------------------------------------------------
extern "C" void kernel_launch(void* const* d_in, const int* in_sizes, int n_in,
                              void* d_out, int out_size, void* d_ws, size_t ws_size,
                              hipStream_t stream) {
  const float* feat = (const float*)d_in[0];
  const float* dw   = (const float*)d_in[1];
  const float* pw   = (const float*)d_in[2];
  float* out = (float*)d_out;

  const size_t YBYTES = (size_t)K_TOT * NSP * 2;   // 64 MiB

  if (ws_size >= 2 * YBYTES) {
    // main path: Yt@0, Yn@64MiB; Wb overlaps dead Yn after transpose
    unsigned short* Yt = (unsigned short*)d_ws;
    unsigned short* Yn = (unsigned short*)((char*)d_ws + YBYTES);
    unsigned short* Wb = Yn;                       // reused after tr_kernel
    dw_kernel<<<dim3(4, 1024), dim3(256), 0, stream>>>(feat, dw, Yn);
    tr_kernel<<<dim3(512, 16), dim3(256), 0, stream>>>(Yn, Yt);
    castw_kernel<<<dim3(1024), dim3(256), 0, stream>>>(pw, Wb);
    gemm_kernel<<<dim3(256, 8), dim3(256), 0, stream>>>(Wb, Yt, out);
  } else {
    // fallback (proven round-3 path, 66 MiB)
    unsigned short* Yn = (unsigned short*)d_ws;
    unsigned short* Wb = Yn + (size_t)K_TOT * NSP;
    dw_kernel<<<dim3(4, 1024), dim3(256), 0, stream>>>(feat, dw, Yn);
    castw_kernel<<<dim3(1024), dim3(256), 0, stream>>>(pw, Wb);
    gemm_nmajor_kernel<<<dim3(256, 8), dim3(256), 0, stream>>>(Wb, Yn, out);
  }
}

// Round 5
// 176.727 us; speedup vs baseline: 2.8213x; 1.0721x over previous
//
#include <hip/hip_runtime.h>
#include <hip/hip_bf16.h>
#include <stdint.h>

typedef __attribute__((ext_vector_type(8))) short s8v;
typedef __attribute__((ext_vector_type(4))) float f4v;

#define T_TOT 8
#define NSP 32768   // T*H*W
#define K_TOT 1024
#define M_TOT 1024

__device__ __forceinline__ unsigned short f2bf(float f) {
  unsigned int u = __float_as_uint(f);
  u += 0x7FFF + ((u >> 16) & 1);   // round-to-nearest-even
  return (unsigned short)(u >> 16);
}

// ---------------------------------------------------------------------------
// Kernel 1 (unchanged, ~35us): depthwise 3x3x3, shared kernel. Block=(h16,c).
// ---------------------------------------------------------------------------
__global__ __launch_bounds__(256) void dw_kernel(const float* __restrict__ X,
                                                 const float* __restrict__ DW,
                                                 unsigned short* __restrict__ Yn) {
  __shared__ float xin[8 * 18 * 64];         // 36 KB  [t][hr][w]
  const int tid = threadIdx.x;
  const int hb  = blockIdx.x;                // 0..3
  const int c   = blockIdx.y;                // 0..1023
  const int h0  = hb * 16;

  float kw[27];
#pragma unroll
  for (int j = 0; j < 27; ++j) kw[j] = DW[j];

  const float* Xc = X + (size_t)c * NSP;

#pragma unroll
  for (int i = 0; i < 9; ++i) {
    const int f  = tid + i * 256;
    const int r  = f >> 4;
    const int wq = (f & 15) * 4;
    const int t  = r / 18;
    const int hr = r - t * 18;
    const int hg = h0 - 1 + hr;
    const int hc = min(max(hg, 0), 63);
    float4 v = *(const float4*)(Xc + (t * 64 + hc) * 64 + wq);
    if (hg != hc) v = (float4){0.f, 0.f, 0.f, 0.f};
    *(float4*)&xin[r * 64 + wq] = v;
  }
  __syncthreads();

  const int w  = tid & 63;
  const int hq = tid >> 6;
  const int wl = (w == 0)  ? w : w - 1;
  const int wr = (w == 63) ? w : w + 1;
  const float* bC = &xin[(hq * 4) * 64 + w];
  const float* bL = &xin[(hq * 4) * 64 + wl];
  const float* bR = &xin[(hq * 4) * 64 + wr];
  unsigned short* Yb = Yn + (size_t)c * NSP + (h0 + hq * 4) * 64 + w;

  float a0[4], a1[4], a2[4];
#pragma unroll
  for (int j = 0; j < 4; ++j) { a0[j] = 0.f; a1[j] = 0.f; a2[j] = 0.f; }

#pragma unroll
  for (int tp = 0; tp < 8; ++tp) {
    float v[6][3];
#pragma unroll
    for (int rr = 0; rr < 6; ++rr) {
      const int off = (tp * 18 + rr) * 64;
      float xc = bC[off];
      float xl = bL[off];
      float xr = bR[off];
      if (w == 0)  xl = 0.f;
      if (w == 63) xr = 0.f;
      v[rr][0] = xl; v[rr][1] = xc; v[rr][2] = xr;
    }
#pragma unroll
    for (int j = 0; j < 4; ++j)
#pragma unroll
      for (int kh = 0; kh < 3; ++kh)
#pragma unroll
        for (int kd = 0; kd < 3; ++kd) {
          const float xv = v[j + kh][kd];
          if (tp >= 1) a0[j] += kw[(2 * 3 + kh) * 3 + kd] * xv;
          a1[j] += kw[(1 * 3 + kh) * 3 + kd] * xv;
          if (tp <= 6) a2[j] += kw[(0 * 3 + kh) * 3 + kd] * xv;
        }
    if (tp >= 1) {
      unsigned short* yp = Yb + (size_t)(tp - 1) * 4096;
#pragma unroll
      for (int j = 0; j < 4; ++j) yp[j * 64] = f2bf(a0[j]);
    }
#pragma unroll
    for (int j = 0; j < 4; ++j) { a0[j] = a1[j]; a1[j] = a2[j]; a2[j] = 0.f; }
  }
  {
    unsigned short* yp = Yb + (size_t)7 * 4096;
#pragma unroll
    for (int j = 0; j < 4; ++j) yp[j * 64] = f2bf(a0[j]);
  }
}

// ---------------------------------------------------------------------------
// Kernel 1b (unchanged, ~22us): transpose Yn[c][n] -> Yt[n][c], 64x64 tiles.
// ---------------------------------------------------------------------------
__global__ __launch_bounds__(256) void tr_kernel(const unsigned short* __restrict__ Yn,
                                                 unsigned short* __restrict__ Yt) {
  __shared__ unsigned short tb[64][68];
  const int tid = threadIdx.x;
  const int n0  = blockIdx.x * 64;
  const int c0  = blockIdx.y * 64;

#pragma unroll
  for (int i = 0; i < 2; ++i) {
    const int cl = (tid >> 3) + i * 32;
    const int n8 = (tid & 7) * 8;
    const uint4 v = *(const uint4*)(Yn + (size_t)(c0 + cl) * NSP + n0 + n8);
    uint2 lo; lo.x = v.x; lo.y = v.y;
    uint2 hi; hi.x = v.z; hi.y = v.w;
    *(uint2*)&tb[cl][n8]     = lo;
    *(uint2*)&tb[cl][n8 + 4] = hi;
  }
  __syncthreads();

  const int nl = tid >> 2;
  const int cq = tid & 3;
#pragma unroll
  for (int i = 0; i < 2; ++i) {
    const int c8 = cq * 8 + i * 32;
    unsigned int p[4];
#pragma unroll
    for (int j = 0; j < 4; ++j) {
      const unsigned int a = tb[c8 + 2 * j][nl];
      const unsigned int b = tb[c8 + 2 * j + 1][nl];
      p[j] = a | (b << 16);
    }
    uint4 o; o.x = p[0]; o.y = p[1]; o.z = p[2]; o.w = p[3];
    *(uint4*)(Yt + (size_t)(n0 + nl) * 1024 + c0 + c8) = o;
  }
}

// ---------------------------------------------------------------------------
// Kernel 2: pointwise weight fp32 -> bf16
// ---------------------------------------------------------------------------
__global__ __launch_bounds__(256) void castw_kernel(const float* __restrict__ Wf,
                                                    unsigned short* __restrict__ Wb) {
  const int i = (blockIdx.x * 256 + threadIdx.x) * 4;
  float4 v = *(const float4*)&Wf[i];
  ushort4 o;
  o.x = f2bf(v.x); o.y = f2bf(v.y); o.z = f2bf(v.z); o.w = f2bf(v.w);
  *(ushort4*)&Wb[i] = o;
}

// ---------------------------------------------------------------------------
// Kernel 3 (v2): C = A[M][K] * Bt[N][K]^T, 128x128 tile, BK=32.
// New vs round-4: (a) double-buffered LDS, prefetch issued BEFORE compute,
// single __syncthreads (vmcnt drain) per K-step = T3 minimum-2-phase;
// (b) XOR swizzle col16 ^= (row>>1)&3 applied on BOTH the pre-swizzled
// global source k-offset and the ds_read col (LDS stays linear for
// global_load_lds) -> 8-way b128 bank conflict -> 2-way (free);
// (c) XCD-bijective grid remap, bm fastest: 8 adjacent wgs share a B-tile.
// ---------------------------------------------------------------------------
__device__ __forceinline__ void gload_lds16(const void* g, void* lds) {
  __builtin_amdgcn_global_load_lds(
      (const __attribute__((address_space(1))) void*)(uintptr_t)g,
      (__attribute__((address_space(3))) void*)(uintptr_t)lds, 16, 0, 0);
}

__global__ __launch_bounds__(256) void gemm_kernel(const unsigned short* __restrict__ A,
                                                   const unsigned short* __restrict__ B,
                                                   float* __restrict__ C) {
  __shared__ unsigned short As[2][128][32];   // 16 KB
  __shared__ unsigned short Bs[2][128][32];   // 16 KB
  const int tid  = threadIdx.x;
  const int lane = tid & 63;
  const int wv   = tid >> 6;
  const int wr   = wv >> 1, wc = wv & 1;

  // XCD-aware remap (2048 wgs / 8 XCDs): XCD x gets logical x*256..x*256+255,
  // decomposed bm = lg&7 (fastest), bn = lg>>3 -> per-XCD contiguous bn chunk.
  const int wg = (int)blockIdx.x;
  const int lg = (wg & 7) * 256 + (wg >> 3);
  const int bm = lg & 7;
  const int bn = lg >> 3;

  f4v acc[4][4];
#pragma unroll
  for (int i = 0; i < 4; ++i)
#pragma unroll
    for (int j = 0; j < 4; ++j) acc[i][j] = (f4v){0.f, 0.f, 0.f, 0.f};

  const int r  = tid >> 2;                                   // tile row
  const int kb = (((tid & 3) ^ ((tid >> 3) & 3)) * 8);       // swizzled k-col
  const unsigned short* ga0 = A + (size_t)(bm * 128 + r) * K_TOT + kb;
  const unsigned short* gb0 = B + (size_t)(bn * 128 + r) * K_TOT + kb;

  // prologue: stage K-tile 0 into buffer 0
  {
    char* ad = (char*)(&As[0][0][0]) + wv * 1024;
    char* bd = (char*)(&Bs[0][0][0]) + wv * 1024;
    gload_lds16(ga0,                ad);
    gload_lds16(ga0 + 64 * K_TOT,   ad + 4096);
    gload_lds16(gb0,                bd);
    gload_lds16(gb0 + 64 * K_TOT,   bd + 4096);
  }
  __syncthreads();

  const int cphys = ((lane >> 4) ^ ((lane >> 1) & 3)) * 8;   // swizzled read col
  int cur = 0;
#pragma unroll 2
  for (int kt = 0; kt < K_TOT; kt += 32) {
    if (kt + 32 < K_TOT) {                   // issue next-tile loads FIRST
      const int nxt = cur ^ 1;
      char* ad = (char*)(&As[nxt][0][0]) + wv * 1024;
      char* bd = (char*)(&Bs[nxt][0][0]) + wv * 1024;
      gload_lds16(ga0 + kt + 32,              ad);
      gload_lds16(ga0 + 64 * K_TOT + kt + 32, ad + 4096);
      gload_lds16(gb0 + kt + 32,              bd);
      gload_lds16(gb0 + 64 * K_TOT + kt + 32, bd + 4096);
    }
    s8v a[4], b[4];
#pragma unroll
    for (int mf = 0; mf < 4; ++mf)
      a[mf] = *(const s8v*)&As[cur][wr * 64 + mf * 16 + (lane & 15)][cphys];
#pragma unroll
    for (int nf = 0; nf < 4; ++nf)
      b[nf] = *(const s8v*)&Bs[cur][wc * 64 + nf * 16 + (lane & 15)][cphys];
#pragma unroll
    for (int mf = 0; mf < 4; ++mf)
#pragma unroll
      for (int nf = 0; nf < 4; ++nf)
        acc[mf][nf] = __builtin_amdgcn_mfma_f32_16x16x32_bf16(a[mf], b[nf], acc[mf][nf], 0, 0, 0);
    __syncthreads();                         // one drain+barrier per K-step
    cur ^= 1;
  }

  const int rowq = (lane >> 4) * 4;
  const int colq = lane & 15;
#pragma unroll
  for (int mf = 0; mf < 4; ++mf) {
    const int row0 = bm * 128 + wr * 64 + mf * 16 + rowq;
#pragma unroll
    for (int nf = 0; nf < 4; ++nf) {
      const int col = bn * 128 + wc * 64 + nf * 16 + colq;
      float* cp = C + (size_t)row0 * NSP + col;
#pragma unroll
      for (int j = 0; j < 4; ++j) cp[(size_t)j * NSP] = acc[mf][nf][j];
    }
  }
}

// ---------------------------------------------------------------------------
// Fallback GEMM (round-3 verbatim): used only if ws can't fit Yn+Yt.
// ---------------------------------------------------------------------------
__global__ __launch_bounds__(256) void gemm_nmajor_kernel(const unsigned short* __restrict__ A,
                                                          const unsigned short* __restrict__ B,
                                                          float* __restrict__ C) {
  __shared__ unsigned short As[128][32];
  __shared__ unsigned short Bs[128][40];
  const int tid  = threadIdx.x;
  const int lane = tid & 63;
  const int wv   = tid >> 6;
  const int wr   = wv >> 1, wc = wv & 1;
  const int bn   = blockIdx.x, bm = blockIdx.y;
  const int n0   = bn * 128;

  f4v acc[4][4];
#pragma unroll
  for (int i = 0; i < 4; ++i)
#pragma unroll
    for (int j = 0; j < 4; ++j) acc[i][j] = (f4v){0.f, 0.f, 0.f, 0.f};

  const int r  = tid >> 2;
  const int kb = (tid & 3) * 8;
  const unsigned short* ga0 = A + (size_t)(bm * 128 + r) * K_TOT + kb;
  char* ldsA = (char*)(&As[0][0]) + wv * 1024;
  const int nq4 = (tid >> 3) * 4;
  const int kq4 = (tid & 7) * 4;

  for (int kt = 0; kt < K_TOT; kt += 32) {
    __syncthreads();
    gload_lds16(ga0 + kt,               ldsA);
    gload_lds16(ga0 + 64 * K_TOT + kt,  ldsA + 4096);

    const unsigned short* gB = B + (size_t)(kt + kq4) * NSP + n0 + nq4;
    uint2 L0 = *(const uint2*)(gB);
    uint2 L1 = *(const uint2*)(gB + NSP);
    uint2 L2 = *(const uint2*)(gB + 2 * NSP);
    uint2 L3 = *(const uint2*)(gB + 3 * NSP);
    uint2 W0, W1, W2, W3;
    W0.x = (L0.x & 0xFFFFu) | (L1.x << 16);
    W0.y = (L2.x & 0xFFFFu) | (L3.x << 16);
    W1.x = (L0.x >> 16) | (L1.x & 0xFFFF0000u);
    W1.y = (L2.x >> 16) | (L3.x & 0xFFFF0000u);
    W2.x = (L0.y & 0xFFFFu) | (L1.y << 16);
    W2.y = (L2.y & 0xFFFFu) | (L3.y << 16);
    W3.x = (L0.y >> 16) | (L1.y & 0xFFFF0000u);
    W3.y = (L2.y >> 16) | (L3.y & 0xFFFF0000u);
    *(uint2*)&Bs[nq4 + 0][kq4] = W0;
    *(uint2*)&Bs[nq4 + 1][kq4] = W1;
    *(uint2*)&Bs[nq4 + 2][kq4] = W2;
    *(uint2*)&Bs[nq4 + 3][kq4] = W3;
    __syncthreads();

    s8v a[4], b[4];
#pragma unroll
    for (int mf = 0; mf < 4; ++mf)
      a[mf] = *(const s8v*)&As[wr * 64 + mf * 16 + (lane & 15)][(lane >> 4) * 8];
#pragma unroll
    for (int nf = 0; nf < 4; ++nf)
      b[nf] = *(const s8v*)&Bs[wc * 64 + nf * 16 + (lane & 15)][(lane >> 4) * 8];
#pragma unroll
    for (int mf = 0; mf < 4; ++mf)
#pragma unroll
      for (int nf = 0; nf < 4; ++nf)
        acc[mf][nf] = __builtin_amdgcn_mfma_f32_16x16x32_bf16(a[mf], b[nf], acc[mf][nf], 0, 0, 0);
  }

  const int rowq = (lane >> 4) * 4;
  const int colq = lane & 15;
#pragma unroll
  for (int mf = 0; mf < 4; ++mf) {
    const int row0 = bm * 128 + wr * 64 + mf * 16 + rowq;
#pragma unroll
    for (int nf = 0; nf < 4; ++nf) {
      const int col = n0 + wc * 64 + nf * 16 + colq;
      float* cp = C + (size_t)row0 * NSP + col;
#pragma unroll
      for (int j = 0; j < 4; ++j) cp[(size_t)j * NSP] = acc[mf][nf][j];
    }
  }
}

// ---------------------------------------------------------------------------
extern "C" void kernel_launch(void* const* d_in, const int* in_sizes, int n_in,
                              void* d_out, int out_size, void* d_ws, size_t ws_size,
                              hipStream_t stream) {
  const float* feat = (const float*)d_in[0];
  const float* dw   = (const float*)d_in[1];
  const float* pw   = (const float*)d_in[2];
  float* out = (float*)d_out;

  const size_t YBYTES = (size_t)K_TOT * NSP * 2;   // 64 MiB

  if (ws_size >= 2 * YBYTES) {
    unsigned short* Yt = (unsigned short*)d_ws;
    unsigned short* Yn = (unsigned short*)((char*)d_ws + YBYTES);
    unsigned short* Wb = Yn;                       // reused after tr_kernel
    dw_kernel<<<dim3(4, 1024), dim3(256), 0, stream>>>(feat, dw, Yn);
    tr_kernel<<<dim3(512, 16), dim3(256), 0, stream>>>(Yn, Yt);
    castw_kernel<<<dim3(1024), dim3(256), 0, stream>>>(pw, Wb);
    gemm_kernel<<<dim3(2048), dim3(256), 0, stream>>>(Wb, Yt, out);
  } else {
    unsigned short* Yn = (unsigned short*)d_ws;
    unsigned short* Wb = Yn + (size_t)K_TOT * NSP;
    dw_kernel<<<dim3(4, 1024), dim3(256), 0, stream>>>(feat, dw, Yn);
    castw_kernel<<<dim3(1024), dim3(256), 0, stream>>>(pw, Wb);
    gemm_nmajor_kernel<<<dim3(256, 8), dim3(256), 0, stream>>>(Wb, Yn, out);
  }
}

// Round 6
// 168.747 us; speedup vs baseline: 2.9547x; 1.0473x over previous
//
#include <hip/hip_runtime.h>
#include <hip/hip_bf16.h>
#include <stdint.h>

typedef __attribute__((ext_vector_type(8))) short s8v;
typedef __attribute__((ext_vector_type(4))) float f4v;

#define T_TOT 8
#define NSP 32768   // T*H*W
#define K_TOT 1024
#define M_TOT 1024

__device__ __forceinline__ unsigned short f2bf(float f) {
  unsigned int u = __float_as_uint(f);
  u += 0x7FFF + ((u >> 16) & 1);   // round-to-nearest-even
  return (unsigned short)(u >> 16);
}

// ---------------------------------------------------------------------------
// Kernel 1 (unchanged, ~35us, at its BW floor): depthwise 3x3x3.
// ---------------------------------------------------------------------------
__global__ __launch_bounds__(256) void dw_kernel(const float* __restrict__ X,
                                                 const float* __restrict__ DW,
                                                 unsigned short* __restrict__ Yn) {
  __shared__ float xin[8 * 18 * 64];         // 36 KB  [t][hr][w]
  const int tid = threadIdx.x;
  const int hb  = blockIdx.x;                // 0..3
  const int c   = blockIdx.y;                // 0..1023
  const int h0  = hb * 16;

  float kw[27];
#pragma unroll
  for (int j = 0; j < 27; ++j) kw[j] = DW[j];

  const float* Xc = X + (size_t)c * NSP;

#pragma unroll
  for (int i = 0; i < 9; ++i) {
    const int f  = tid + i * 256;
    const int r  = f >> 4;
    const int wq = (f & 15) * 4;
    const int t  = r / 18;
    const int hr = r - t * 18;
    const int hg = h0 - 1 + hr;
    const int hc = min(max(hg, 0), 63);
    float4 v = *(const float4*)(Xc + (t * 64 + hc) * 64 + wq);
    if (hg != hc) v = (float4){0.f, 0.f, 0.f, 0.f};
    *(float4*)&xin[r * 64 + wq] = v;
  }
  __syncthreads();

  const int w  = tid & 63;
  const int hq = tid >> 6;
  const int wl = (w == 0)  ? w : w - 1;
  const int wr = (w == 63) ? w : w + 1;
  const float* bC = &xin[(hq * 4) * 64 + w];
  const float* bL = &xin[(hq * 4) * 64 + wl];
  const float* bR = &xin[(hq * 4) * 64 + wr];
  unsigned short* Yb = Yn + (size_t)c * NSP + (h0 + hq * 4) * 64 + w;

  float a0[4], a1[4], a2[4];
#pragma unroll
  for (int j = 0; j < 4; ++j) { a0[j] = 0.f; a1[j] = 0.f; a2[j] = 0.f; }

#pragma unroll
  for (int tp = 0; tp < 8; ++tp) {
    float v[6][3];
#pragma unroll
    for (int rr = 0; rr < 6; ++rr) {
      const int off = (tp * 18 + rr) * 64;
      float xc = bC[off];
      float xl = bL[off];
      float xr = bR[off];
      if (w == 0)  xl = 0.f;
      if (w == 63) xr = 0.f;
      v[rr][0] = xl; v[rr][1] = xc; v[rr][2] = xr;
    }
#pragma unroll
    for (int j = 0; j < 4; ++j)
#pragma unroll
      for (int kh = 0; kh < 3; ++kh)
#pragma unroll
        for (int kd = 0; kd < 3; ++kd) {
          const float xv = v[j + kh][kd];
          if (tp >= 1) a0[j] += kw[(2 * 3 + kh) * 3 + kd] * xv;
          a1[j] += kw[(1 * 3 + kh) * 3 + kd] * xv;
          if (tp <= 6) a2[j] += kw[(0 * 3 + kh) * 3 + kd] * xv;
        }
    if (tp >= 1) {
      unsigned short* yp = Yb + (size_t)(tp - 1) * 4096;
#pragma unroll
      for (int j = 0; j < 4; ++j) yp[j * 64] = f2bf(a0[j]);
    }
#pragma unroll
    for (int j = 0; j < 4; ++j) { a0[j] = a1[j]; a1[j] = a2[j]; a2[j] = 0.f; }
  }
  {
    unsigned short* yp = Yb + (size_t)7 * 4096;
#pragma unroll
    for (int j = 0; j < 4; ++j) yp[j * 64] = f2bf(a0[j]);
  }
}

// ---------------------------------------------------------------------------
// Kernel 1b (unchanged, ~22us, at BW floor): transpose Yn[c][n] -> Yt[n][c].
// ---------------------------------------------------------------------------
__global__ __launch_bounds__(256) void tr_kernel(const unsigned short* __restrict__ Yn,
                                                 unsigned short* __restrict__ Yt) {
  __shared__ unsigned short tb[64][68];
  const int tid = threadIdx.x;
  const int n0  = blockIdx.x * 64;
  const int c0  = blockIdx.y * 64;

#pragma unroll
  for (int i = 0; i < 2; ++i) {
    const int cl = (tid >> 3) + i * 32;
    const int n8 = (tid & 7) * 8;
    const uint4 v = *(const uint4*)(Yn + (size_t)(c0 + cl) * NSP + n0 + n8);
    uint2 lo; lo.x = v.x; lo.y = v.y;
    uint2 hi; hi.x = v.z; hi.y = v.w;
    *(uint2*)&tb[cl][n8]     = lo;
    *(uint2*)&tb[cl][n8 + 4] = hi;
  }
  __syncthreads();

  const int nl = tid >> 2;
  const int cq = tid & 3;
#pragma unroll
  for (int i = 0; i < 2; ++i) {
    const int c8 = cq * 8 + i * 32;
    unsigned int p[4];
#pragma unroll
    for (int j = 0; j < 4; ++j) {
      const unsigned int a = tb[c8 + 2 * j][nl];
      const unsigned int b = tb[c8 + 2 * j + 1][nl];
      p[j] = a | (b << 16);
    }
    uint4 o; o.x = p[0]; o.y = p[1]; o.z = p[2]; o.w = p[3];
    *(uint4*)(Yt + (size_t)(n0 + nl) * 1024 + c0 + c8) = o;
  }
}

// ---------------------------------------------------------------------------
// Kernel 2: pointwise weight fp32 -> bf16
// ---------------------------------------------------------------------------
__global__ __launch_bounds__(256) void castw_kernel(const float* __restrict__ Wf,
                                                    unsigned short* __restrict__ Wb) {
  const int i = (blockIdx.x * 256 + threadIdx.x) * 4;
  float4 v = *(const float4*)&Wf[i];
  ushort4 o;
  o.x = f2bf(v.x); o.y = f2bf(v.y); o.z = f2bf(v.z); o.w = f2bf(v.w);
  *(ushort4*)&Wb[i] = o;
}

// ---------------------------------------------------------------------------
// Kernel 3 (v3): C = A[M][K] * Bt[N][K]^T, 128x128 tile, BK=32.
// New vs v2: TRIPLE-buffered LDS + counted s_waitcnt vmcnt(4) + raw
// s_barrier (T3/T4 mechanism).  Ledger per iter k (k=0..29):
//   STAGE(tile k+2 -> slotC)   // slotC freed by iter k-1's barrier
//   COMPUTE(slotA = tile k)    // ds_reads consumed by MFMA before barrier
//   s_waitcnt vmcnt(4)         // own tile-k+1 loads landed (k+2 in flight)
//   s_barrier                  // all waves' tile-k+1 landed -> coherent
//   rotate(A<-B<-C<-A)
// Tail: vmcnt(4)@29 -> vmcnt(0)@30 -> plain compute@31.
// Prefetch window ~2 iterations instead of one compute phase.
// Keeps round-5 swizzle (conflicts=0) and XCD remap (FETCH 57MB).
// ---------------------------------------------------------------------------
__device__ __forceinline__ void gload_lds16(const void* g, void* lds) {
  __builtin_amdgcn_global_load_lds(
      (const __attribute__((address_space(1))) void*)(uintptr_t)g,
      (__attribute__((address_space(3))) void*)(uintptr_t)lds, 16, 0, 0);
}

__global__ __launch_bounds__(256) void gemm_kernel(const unsigned short* __restrict__ A,
                                                   const unsigned short* __restrict__ B,
                                                   float* __restrict__ C) {
  __shared__ char smem[3 * 16384];           // 3 x (As 8KB | Bs 8KB)
  const int tid  = threadIdx.x;
  const int lane = tid & 63;
  const int wv   = tid >> 6;
  const int wr   = wv >> 1, wc = wv & 1;

  const int wg = (int)blockIdx.x;
  const int lg = (wg & 7) * 256 + (wg >> 3);
  const int bm = lg & 7;
  const int bn = lg >> 3;

  f4v acc[4][4];
#pragma unroll
  for (int i = 0; i < 4; ++i)
#pragma unroll
    for (int j = 0; j < 4; ++j) acc[i][j] = (f4v){0.f, 0.f, 0.f, 0.f};

  const int r  = tid >> 2;                                   // tile row
  const int kb = (((tid & 3) ^ ((tid >> 3) & 3)) * 8);       // pre-swizzled k
  const unsigned short* ga0 = A + (size_t)(bm * 128 + r) * K_TOT + kb;
  const unsigned short* gb0 = B + (size_t)(bn * 128 + r) * K_TOT + kb;

  char* s0 = smem;
  char* s1 = smem + 16384;
  char* s2 = smem + 32768;
  const int stgoff = wv * 1024;

#define STAGE(base, t)                                                    \
  do {                                                                    \
    char* ad = (base) + stgoff;                                           \
    char* bd = (base) + 8192 + stgoff;                                    \
    gload_lds16(ga0 + (t) * 32,               ad);                        \
    gload_lds16(ga0 + 64 * K_TOT + (t) * 32,  ad + 4096);                 \
    gload_lds16(gb0 + (t) * 32,               bd);                        \
    gload_lds16(gb0 + 64 * K_TOT + (t) * 32,  bd + 4096);                 \
  } while (0)

  const int cphys = ((lane >> 4) ^ ((lane >> 1) & 3)) * 8;   // swizzled col
  const int arow  = wr * 64 + (lane & 15);
  const int brow  = wc * 64 + (lane & 15);

#define COMP(base)                                                        \
  do {                                                                    \
    const unsigned short* As_ = (const unsigned short*)(base);            \
    const unsigned short* Bs_ = (const unsigned short*)((base) + 8192);   \
    s8v a[4], b[4];                                                       \
    _Pragma("unroll")                                                     \
    for (int mf = 0; mf < 4; ++mf)                                        \
      a[mf] = *(const s8v*)&As_[(arow + mf * 16) * 32 + cphys];           \
    _Pragma("unroll")                                                     \
    for (int nf = 0; nf < 4; ++nf)                                        \
      b[nf] = *(const s8v*)&Bs_[(brow + nf * 16) * 32 + cphys];           \
    _Pragma("unroll")                                                     \
    for (int mf = 0; mf < 4; ++mf)                                        \
      _Pragma("unroll")                                                   \
      for (int nf = 0; nf < 4; ++nf)                                      \
        acc[mf][nf] = __builtin_amdgcn_mfma_f32_16x16x32_bf16(            \
            a[mf], b[nf], acc[mf][nf], 0, 0, 0);                          \
  } while (0)

  // prologue: tiles 0,1 in flight; wait tile 0 only
  STAGE(s0, 0);
  STAGE(s1, 1);
  asm volatile("s_waitcnt vmcnt(4)" ::: "memory");
  __builtin_amdgcn_s_barrier();

#pragma unroll 3
  for (int kt = 0; kt < 30; ++kt) {
    STAGE(s2, kt + 2);
    COMP(s0);
    asm volatile("s_waitcnt vmcnt(4)" ::: "memory");
    __builtin_amdgcn_s_barrier();
    char* t = s0; s0 = s1; s1 = s2; s2 = t;
  }
  // kt = 30: tile 31 is the only one in flight
  COMP(s0);
  asm volatile("s_waitcnt vmcnt(0)" ::: "memory");
  __builtin_amdgcn_s_barrier();
  // kt = 31
  COMP(s1);

#undef STAGE
#undef COMP

  const int rowq = (lane >> 4) * 4;
  const int colq = lane & 15;
#pragma unroll
  for (int mf = 0; mf < 4; ++mf) {
    const int row0 = bm * 128 + wr * 64 + mf * 16 + rowq;
#pragma unroll
    for (int nf = 0; nf < 4; ++nf) {
      const int col = bn * 128 + wc * 64 + nf * 16 + colq;
      float* cp = C + (size_t)row0 * NSP + col;
#pragma unroll
      for (int j = 0; j < 4; ++j) cp[(size_t)j * NSP] = acc[mf][nf][j];
    }
  }
}

// ---------------------------------------------------------------------------
// Fallback GEMM (round-3 verbatim): used only if ws can't fit Yn+Yt.
// ---------------------------------------------------------------------------
__global__ __launch_bounds__(256) void gemm_nmajor_kernel(const unsigned short* __restrict__ A,
                                                          const unsigned short* __restrict__ B,
                                                          float* __restrict__ C) {
  __shared__ unsigned short As[128][32];
  __shared__ unsigned short Bs[128][40];
  const int tid  = threadIdx.x;
  const int lane = tid & 63;
  const int wv   = tid >> 6;
  const int wr   = wv >> 1, wc = wv & 1;
  const int bn   = blockIdx.x, bm = blockIdx.y;
  const int n0   = bn * 128;

  f4v acc[4][4];
#pragma unroll
  for (int i = 0; i < 4; ++i)
#pragma unroll
    for (int j = 0; j < 4; ++j) acc[i][j] = (f4v){0.f, 0.f, 0.f, 0.f};

  const int r  = tid >> 2;
  const int kb = (tid & 3) * 8;
  const unsigned short* ga0 = A + (size_t)(bm * 128 + r) * K_TOT + kb;
  char* ldsA = (char*)(&As[0][0]) + wv * 1024;
  const int nq4 = (tid >> 3) * 4;
  const int kq4 = (tid & 7) * 4;

  for (int kt = 0; kt < K_TOT; kt += 32) {
    __syncthreads();
    gload_lds16(ga0 + kt,               ldsA);
    gload_lds16(ga0 + 64 * K_TOT + kt,  ldsA + 4096);

    const unsigned short* gB = B + (size_t)(kt + kq4) * NSP + n0 + nq4;
    uint2 L0 = *(const uint2*)(gB);
    uint2 L1 = *(const uint2*)(gB + NSP);
    uint2 L2 = *(const uint2*)(gB + 2 * NSP);
    uint2 L3 = *(const uint2*)(gB + 3 * NSP);
    uint2 W0, W1, W2, W3;
    W0.x = (L0.x & 0xFFFFu) | (L1.x << 16);
    W0.y = (L2.x & 0xFFFFu) | (L3.x << 16);
    W1.x = (L0.x >> 16) | (L1.x & 0xFFFF0000u);
    W1.y = (L2.x >> 16) | (L3.x & 0xFFFF0000u);
    W2.x = (L0.y & 0xFFFFu) | (L1.y << 16);
    W2.y = (L2.y & 0xFFFFu) | (L3.y << 16);
    W3.x = (L0.y >> 16) | (L1.y & 0xFFFF0000u);
    W3.y = (L2.y >> 16) | (L3.y & 0xFFFF0000u);
    *(uint2*)&Bs[nq4 + 0][kq4] = W0;
    *(uint2*)&Bs[nq4 + 1][kq4] = W1;
    *(uint2*)&Bs[nq4 + 2][kq4] = W2;
    *(uint2*)&Bs[nq4 + 3][kq4] = W3;
    __syncthreads();

    s8v a[4], b[4];
#pragma unroll
    for (int mf = 0; mf < 4; ++mf)
      a[mf] = *(const s8v*)&As[wr * 64 + mf * 16 + (lane & 15)][(lane >> 4) * 8];
#pragma unroll
    for (int nf = 0; nf < 4; ++nf)
      b[nf] = *(const s8v*)&Bs[wc * 64 + nf * 16 + (lane & 15)][(lane >> 4) * 8];
#pragma unroll
    for (int mf = 0; mf < 4; ++mf)
#pragma unroll
      for (int nf = 0; nf < 4; ++nf)
        acc[mf][nf] = __builtin_amdgcn_mfma_f32_16x16x32_bf16(a[mf], b[nf], acc[mf][nf], 0, 0, 0);
  }

  const int rowq = (lane >> 4) * 4;
  const int colq = lane & 15;
#pragma unroll
  for (int mf = 0; mf < 4; ++mf) {
    const int row0 = bm * 128 + wr * 64 + mf * 16 + rowq;
#pragma unroll
    for (int nf = 0; nf < 4; ++nf) {
      const int col = n0 + wc * 64 + nf * 16 + colq;
      float* cp = C + (size_t)row0 * NSP + col;
#pragma unroll
      for (int j = 0; j < 4; ++j) cp[(size_t)j * NSP] = acc[mf][nf][j];
    }
  }
}

// ---------------------------------------------------------------------------
extern "C" void kernel_launch(void* const* d_in, const int* in_sizes, int n_in,
                              void* d_out, int out_size, void* d_ws, size_t ws_size,
                              hipStream_t stream) {
  const float* feat = (const float*)d_in[0];
  const float* dw   = (const float*)d_in[1];
  const float* pw   = (const float*)d_in[2];
  float* out = (float*)d_out;

  const size_t YBYTES = (size_t)K_TOT * NSP * 2;   // 64 MiB

  if (ws_size >= 2 * YBYTES) {
    unsigned short* Yt = (unsigned short*)d_ws;
    unsigned short* Yn = (unsigned short*)((char*)d_ws + YBYTES);
    unsigned short* Wb = Yn;                       // reused after tr_kernel
    dw_kernel<<<dim3(4, 1024), dim3(256), 0, stream>>>(feat, dw, Yn);
    tr_kernel<<<dim3(512, 16), dim3(256), 0, stream>>>(Yn, Yt);
    castw_kernel<<<dim3(1024), dim3(256), 0, stream>>>(pw, Wb);
    gemm_kernel<<<dim3(2048), dim3(256), 0, stream>>>(Wb, Yt, out);
  } else {
    unsigned short* Yn = (unsigned short*)d_ws;
    unsigned short* Wb = Yn + (size_t)K_TOT * NSP;
    dw_kernel<<<dim3(4, 1024), dim3(256), 0, stream>>>(feat, dw, Yn);
    castw_kernel<<<dim3(1024), dim3(256), 0, stream>>>(pw, Wb);
    gemm_nmajor_kernel<<<dim3(256, 8), dim3(256), 0, stream>>>(Wb, Yn, out);
  }
}

// Round 7
// 156.418 us; speedup vs baseline: 3.1876x; 1.0788x over previous
//
#include <hip/hip_runtime.h>
#include <hip/hip_bf16.h>
#include <stdint.h>

typedef __attribute__((ext_vector_type(8))) short s8v;
typedef __attribute__((ext_vector_type(4))) float f4v;

#define T_TOT 8
#define NSP 32768   // T*H*W
#define K_TOT 1024
#define M_TOT 1024

__device__ __forceinline__ unsigned short f2bf(float f) {
  unsigned int u = __float_as_uint(f);
  u += 0x7FFF + ((u >> 16) & 1);   // round-to-nearest-even
  return (unsigned short)(u >> 16);
}

// ---------------------------------------------------------------------------
// Kernel 1 (unchanged, ~35us, at its BW floor): depthwise 3x3x3.
// ---------------------------------------------------------------------------
__global__ __launch_bounds__(256) void dw_kernel(const float* __restrict__ X,
                                                 const float* __restrict__ DW,
                                                 unsigned short* __restrict__ Yn) {
  __shared__ float xin[8 * 18 * 64];         // 36 KB  [t][hr][w]
  const int tid = threadIdx.x;
  const int hb  = blockIdx.x;                // 0..3
  const int c   = blockIdx.y;                // 0..1023
  const int h0  = hb * 16;

  float kw[27];
#pragma unroll
  for (int j = 0; j < 27; ++j) kw[j] = DW[j];

  const float* Xc = X + (size_t)c * NSP;

#pragma unroll
  for (int i = 0; i < 9; ++i) {
    const int f  = tid + i * 256;
    const int r  = f >> 4;
    const int wq = (f & 15) * 4;
    const int t  = r / 18;
    const int hr = r - t * 18;
    const int hg = h0 - 1 + hr;
    const int hc = min(max(hg, 0), 63);
    float4 v = *(const float4*)(Xc + (t * 64 + hc) * 64 + wq);
    if (hg != hc) v = (float4){0.f, 0.f, 0.f, 0.f};
    *(float4*)&xin[r * 64 + wq] = v;
  }
  __syncthreads();

  const int w  = tid & 63;
  const int hq = tid >> 6;
  const int wl = (w == 0)  ? w : w - 1;
  const int wr = (w == 63) ? w : w + 1;
  const float* bC = &xin[(hq * 4) * 64 + w];
  const float* bL = &xin[(hq * 4) * 64 + wl];
  const float* bR = &xin[(hq * 4) * 64 + wr];
  unsigned short* Yb = Yn + (size_t)c * NSP + (h0 + hq * 4) * 64 + w;

  float a0[4], a1[4], a2[4];
#pragma unroll
  for (int j = 0; j < 4; ++j) { a0[j] = 0.f; a1[j] = 0.f; a2[j] = 0.f; }

#pragma unroll
  for (int tp = 0; tp < 8; ++tp) {
    float v[6][3];
#pragma unroll
    for (int rr = 0; rr < 6; ++rr) {
      const int off = (tp * 18 + rr) * 64;
      float xc = bC[off];
      float xl = bL[off];
      float xr = bR[off];
      if (w == 0)  xl = 0.f;
      if (w == 63) xr = 0.f;
      v[rr][0] = xl; v[rr][1] = xc; v[rr][2] = xr;
    }
#pragma unroll
    for (int j = 0; j < 4; ++j)
#pragma unroll
      for (int kh = 0; kh < 3; ++kh)
#pragma unroll
        for (int kd = 0; kd < 3; ++kd) {
          const float xv = v[j + kh][kd];
          if (tp >= 1) a0[j] += kw[(2 * 3 + kh) * 3 + kd] * xv;
          a1[j] += kw[(1 * 3 + kh) * 3 + kd] * xv;
          if (tp <= 6) a2[j] += kw[(0 * 3 + kh) * 3 + kd] * xv;
        }
    if (tp >= 1) {
      unsigned short* yp = Yb + (size_t)(tp - 1) * 4096;
#pragma unroll
      for (int j = 0; j < 4; ++j) yp[j * 64] = f2bf(a0[j]);
    }
#pragma unroll
    for (int j = 0; j < 4; ++j) { a0[j] = a1[j]; a1[j] = a2[j]; a2[j] = 0.f; }
  }
  {
    unsigned short* yp = Yb + (size_t)7 * 4096;
#pragma unroll
    for (int j = 0; j < 4; ++j) yp[j * 64] = f2bf(a0[j]);
  }
}

// ---------------------------------------------------------------------------
// Kernel 1b (unchanged, ~22us, at BW floor): transpose Yn[c][n] -> Yt[n][c].
// ---------------------------------------------------------------------------
__global__ __launch_bounds__(256) void tr_kernel(const unsigned short* __restrict__ Yn,
                                                 unsigned short* __restrict__ Yt) {
  __shared__ unsigned short tb[64][68];
  const int tid = threadIdx.x;
  const int n0  = blockIdx.x * 64;
  const int c0  = blockIdx.y * 64;

#pragma unroll
  for (int i = 0; i < 2; ++i) {
    const int cl = (tid >> 3) + i * 32;
    const int n8 = (tid & 7) * 8;
    const uint4 v = *(const uint4*)(Yn + (size_t)(c0 + cl) * NSP + n0 + n8);
    uint2 lo; lo.x = v.x; lo.y = v.y;
    uint2 hi; hi.x = v.z; hi.y = v.w;
    *(uint2*)&tb[cl][n8]     = lo;
    *(uint2*)&tb[cl][n8 + 4] = hi;
  }
  __syncthreads();

  const int nl = tid >> 2;
  const int cq = tid & 3;
#pragma unroll
  for (int i = 0; i < 2; ++i) {
    const int c8 = cq * 8 + i * 32;
    unsigned int p[4];
#pragma unroll
    for (int j = 0; j < 4; ++j) {
      const unsigned int a = tb[c8 + 2 * j][nl];
      const unsigned int b = tb[c8 + 2 * j + 1][nl];
      p[j] = a | (b << 16);
    }
    uint4 o; o.x = p[0]; o.y = p[1]; o.z = p[2]; o.w = p[3];
    *(uint4*)(Yt + (size_t)(n0 + nl) * 1024 + c0 + c8) = o;
  }
}

// ---------------------------------------------------------------------------
// Kernel 2: pointwise weight fp32 -> bf16
// ---------------------------------------------------------------------------
__global__ __launch_bounds__(256) void castw_kernel(const float* __restrict__ Wf,
                                                    unsigned short* __restrict__ Wb) {
  const int i = (blockIdx.x * 256 + threadIdx.x) * 4;
  float4 v = *(const float4*)&Wf[i];
  ushort4 o;
  o.x = f2bf(v.x); o.y = f2bf(v.y); o.z = f2bf(v.z); o.w = f2bf(v.w);
  *(ushort4*)&Wb[i] = o;
}

// ---------------------------------------------------------------------------
// Kernel 3 (v4): C = A[M][K] * Bt[N][K]^T.  Block tile 256Mx128N, 4 waves,
// wave-tile 128x64 (acc[8][4]).  Per K-step: 12 ds_read_b128 per 32 MFMA
// (0.375 reads/MFMA vs 0.5 in v3) -> LDS-port term ~31us.  Staging: 6
// global_load_lds/thread/tile (4 A-chunks + 2 B-chunks), same verified
// both-sides swizzle (0 conflicts) and 3-buffer counted-vmcnt(6) ledger:
//   STAGE(t+2 -> sC); COMP(sA=t); vmcnt(6)[t+1 landed]; barrier; rotate.
// LDS 3 x 24KB = 72KB -> 2 blocks/CU.  Grid 1024, bijective XCD remap,
// bm fastest (4 consecutive wgs share one 256KB B-panel; A is L2-resident).
// ---------------------------------------------------------------------------
__device__ __forceinline__ void gload_lds16(const void* g, void* lds) {
  __builtin_amdgcn_global_load_lds(
      (const __attribute__((address_space(1))) void*)(uintptr_t)g,
      (__attribute__((address_space(3))) void*)(uintptr_t)lds, 16, 0, 0);
}

__global__ __launch_bounds__(256, 2) void gemm_kernel(const unsigned short* __restrict__ A,
                                                      const unsigned short* __restrict__ B,
                                                      float* __restrict__ C) {
  __shared__ char smem[3 * 24576];           // 3 x (As 16KB | Bs 8KB) = 72KB
  const int tid  = threadIdx.x;
  const int lane = tid & 63;
  const int wv   = tid >> 6;
  const int wr   = wv >> 1, wc = wv & 1;     // wave tile: (wr of 2) x (wc of 2)

  // bijective XCD remap: 1024 wgs, 128 per XCD; bm fastest.
  const int wg = (int)blockIdx.x;
  const int lg = (wg & 7) * 128 + (wg >> 3);
  const int bm = lg & 3;                     // 0..3   (M/256)
  const int bn = lg >> 2;                    // 0..255 (N/128)

  f4v acc[8][4];
#pragma unroll
  for (int i = 0; i < 8; ++i)
#pragma unroll
    for (int j = 0; j < 4; ++j) acc[i][j] = (f4v){0.f, 0.f, 0.f, 0.f};

  const int r  = tid >> 2;                                   // 0..63
  const int kb = (((tid & 3) ^ ((tid >> 3) & 3)) * 8);       // pre-swizzled k
  const unsigned short* ga0 = A + (size_t)(bm * 256 + r) * K_TOT + kb;
  const unsigned short* gb0 = B + (size_t)(bn * 128 + r) * K_TOT + kb;

  char* s0 = smem;
  char* s1 = smem + 24576;
  char* s2 = smem + 49152;
  const int stgoff = wv * 1024;

#define STAGE(base, t)                                                    \
  do {                                                                    \
    char* ad = (base) + stgoff;                                           \
    char* bd = (base) + 16384 + stgoff;                                   \
    gload_lds16(ga0 + (t) * 32,                ad);                       \
    gload_lds16(ga0 + 64 * K_TOT + (t) * 32,   ad + 4096);                \
    gload_lds16(ga0 + 128 * K_TOT + (t) * 32,  ad + 8192);                \
    gload_lds16(ga0 + 192 * K_TOT + (t) * 32,  ad + 12288);               \
    gload_lds16(gb0 + (t) * 32,                bd);                       \
    gload_lds16(gb0 + 64 * K_TOT + (t) * 32,   bd + 4096);                \
  } while (0)

  const int cphys = ((lane >> 4) ^ ((lane >> 1) & 3)) * 8;   // swizzled col
  const int arow  = wr * 128 + (lane & 15);
  const int brow  = wc * 64 + (lane & 15);

#define COMP(base)                                                        \
  do {                                                                    \
    const unsigned short* As_ = (const unsigned short*)(base);            \
    const unsigned short* Bs_ = (const unsigned short*)((base) + 16384);  \
    s8v a[8], b[4];                                                       \
    _Pragma("unroll")                                                     \
    for (int nf = 0; nf < 4; ++nf)                                        \
      b[nf] = *(const s8v*)&Bs_[(brow + nf * 16) * 32 + cphys];           \
    _Pragma("unroll")                                                     \
    for (int mf = 0; mf < 8; ++mf)                                        \
      a[mf] = *(const s8v*)&As_[(arow + mf * 16) * 32 + cphys];           \
    _Pragma("unroll")                                                     \
    for (int mf = 0; mf < 8; ++mf)                                        \
      _Pragma("unroll")                                                   \
      for (int nf = 0; nf < 4; ++nf)                                      \
        acc[mf][nf] = __builtin_amdgcn_mfma_f32_16x16x32_bf16(            \
            a[mf], b[nf], acc[mf][nf], 0, 0, 0);                          \
  } while (0)

  // prologue: tiles 0,1 in flight (12 loads); wait tile 0 (leave 6)
  STAGE(s0, 0);
  STAGE(s1, 1);
  asm volatile("s_waitcnt vmcnt(6)" ::: "memory");
  __builtin_amdgcn_s_barrier();

#pragma unroll 3
  for (int kt = 0; kt < 30; ++kt) {
    STAGE(s2, kt + 2);
    COMP(s0);
    asm volatile("s_waitcnt vmcnt(6)" ::: "memory");
    __builtin_amdgcn_s_barrier();
    char* t = s0; s0 = s1; s1 = s2; s2 = t;
  }
  // kt = 30: tile 31 is the only one in flight
  COMP(s0);
  asm volatile("s_waitcnt vmcnt(0)" ::: "memory");
  __builtin_amdgcn_s_barrier();
  // kt = 31
  COMP(s1);

#undef STAGE
#undef COMP

  const int rowq = (lane >> 4) * 4;
  const int colq = lane & 15;
#pragma unroll
  for (int mf = 0; mf < 8; ++mf) {
    const int row0 = bm * 256 + wr * 128 + mf * 16 + rowq;
#pragma unroll
    for (int nf = 0; nf < 4; ++nf) {
      const int col = bn * 128 + wc * 64 + nf * 16 + colq;
      float* cp = C + (size_t)row0 * NSP + col;
#pragma unroll
      for (int j = 0; j < 4; ++j) cp[(size_t)j * NSP] = acc[mf][nf][j];
    }
  }
}

// ---------------------------------------------------------------------------
// Fallback GEMM (round-3 verbatim): used only if ws can't fit Yn+Yt.
// ---------------------------------------------------------------------------
__global__ __launch_bounds__(256) void gemm_nmajor_kernel(const unsigned short* __restrict__ A,
                                                          const unsigned short* __restrict__ B,
                                                          float* __restrict__ C) {
  __shared__ unsigned short As[128][32];
  __shared__ unsigned short Bs[128][40];
  const int tid  = threadIdx.x;
  const int lane = tid & 63;
  const int wv   = tid >> 6;
  const int wr   = wv >> 1, wc = wv & 1;
  const int bn   = blockIdx.x, bm = blockIdx.y;
  const int n0   = bn * 128;

  f4v acc[4][4];
#pragma unroll
  for (int i = 0; i < 4; ++i)
#pragma unroll
    for (int j = 0; j < 4; ++j) acc[i][j] = (f4v){0.f, 0.f, 0.f, 0.f};

  const int r  = tid >> 2;
  const int kb = (tid & 3) * 8;
  const unsigned short* ga0 = A + (size_t)(bm * 128 + r) * K_TOT + kb;
  char* ldsA = (char*)(&As[0][0]) + wv * 1024;
  const int nq4 = (tid >> 3) * 4;
  const int kq4 = (tid & 7) * 4;

  for (int kt = 0; kt < K_TOT; kt += 32) {
    __syncthreads();
    gload_lds16(ga0 + kt,               ldsA);
    gload_lds16(ga0 + 64 * K_TOT + kt,  ldsA + 4096);

    const unsigned short* gB = B + (size_t)(kt + kq4) * NSP + n0 + nq4;
    uint2 L0 = *(const uint2*)(gB);
    uint2 L1 = *(const uint2*)(gB + NSP);
    uint2 L2 = *(const uint2*)(gB + 2 * NSP);
    uint2 L3 = *(const uint2*)(gB + 3 * NSP);
    uint2 W0, W1, W2, W3;
    W0.x = (L0.x & 0xFFFFu) | (L1.x << 16);
    W0.y = (L2.x & 0xFFFFu) | (L3.x << 16);
    W1.x = (L0.x >> 16) | (L1.x & 0xFFFF0000u);
    W1.y = (L2.x >> 16) | (L3.x & 0xFFFF0000u);
    W2.x = (L0.y & 0xFFFFu) | (L1.y << 16);
    W2.y = (L2.y & 0xFFFFu) | (L3.y << 16);
    W3.x = (L0.y >> 16) | (L1.y & 0xFFFF0000u);
    W3.y = (L2.y >> 16) | (L3.y & 0xFFFF0000u);
    *(uint2*)&Bs[nq4 + 0][kq4] = W0;
    *(uint2*)&Bs[nq4 + 1][kq4] = W1;
    *(uint2*)&Bs[nq4 + 2][kq4] = W2;
    *(uint2*)&Bs[nq4 + 3][kq4] = W3;
    __syncthreads();

    s8v a[4], b[4];
#pragma unroll
    for (int mf = 0; mf < 4; ++mf)
      a[mf] = *(const s8v*)&As[wr * 64 + mf * 16 + (lane & 15)][(lane >> 4) * 8];
#pragma unroll
    for (int nf = 0; nf < 4; ++nf)
      b[nf] = *(const s8v*)&Bs[wc * 64 + nf * 16 + (lane & 15)][(lane >> 4) * 8];
#pragma unroll
    for (int mf = 0; mf < 4; ++mf)
#pragma unroll
      for (int nf = 0; nf < 4; ++nf)
        acc[mf][nf] = __builtin_amdgcn_mfma_f32_16x16x32_bf16(a[mf], b[nf], acc[mf][nf], 0, 0, 0);
  }

  const int rowq = (lane >> 4) * 4;
  const int colq = lane & 15;
#pragma unroll
  for (int mf = 0; mf < 4; ++mf) {
    const int row0 = bm * 128 + wr * 64 + mf * 16 + rowq;
#pragma unroll
    for (int nf = 0; nf < 4; ++nf) {
      const int col = n0 + wc * 64 + nf * 16 + colq;
      float* cp = C + (size_t)row0 * NSP + col;
#pragma unroll
      for (int j = 0; j < 4; ++j) cp[(size_t)j * NSP] = acc[mf][nf][j];
    }
  }
}

// ---------------------------------------------------------------------------
extern "C" void kernel_launch(void* const* d_in, const int* in_sizes, int n_in,
                              void* d_out, int out_size, void* d_ws, size_t ws_size,
                              hipStream_t stream) {
  const float* feat = (const float*)d_in[0];
  const float* dw   = (const float*)d_in[1];
  const float* pw   = (const float*)d_in[2];
  float* out = (float*)d_out;

  const size_t YBYTES = (size_t)K_TOT * NSP * 2;   // 64 MiB

  if (ws_size >= 2 * YBYTES) {
    unsigned short* Yt = (unsigned short*)d_ws;
    unsigned short* Yn = (unsigned short*)((char*)d_ws + YBYTES);
    unsigned short* Wb = Yn;                       // reused after tr_kernel
    dw_kernel<<<dim3(4, 1024), dim3(256), 0, stream>>>(feat, dw, Yn);
    tr_kernel<<<dim3(512, 16), dim3(256), 0, stream>>>(Yn, Yt);
    castw_kernel<<<dim3(1024), dim3(256), 0, stream>>>(pw, Wb);
    gemm_kernel<<<dim3(1024), dim3(256), 0, stream>>>(Wb, Yt, out);
  } else {
    unsigned short* Yn = (unsigned short*)d_ws;
    unsigned short* Wb = Yn + (size_t)K_TOT * NSP;
    dw_kernel<<<dim3(4, 1024), dim3(256), 0, stream>>>(feat, dw, Yn);
    castw_kernel<<<dim3(1024), dim3(256), 0, stream>>>(pw, Wb);
    gemm_nmajor_kernel<<<dim3(256, 8), dim3(256), 0, stream>>>(Wb, Yn, out);
  }
}

// Round 8
// 154.222 us; speedup vs baseline: 3.2330x; 1.0142x over previous
//
#include <hip/hip_runtime.h>
#include <hip/hip_bf16.h>
#include <stdint.h>

typedef __attribute__((ext_vector_type(8))) short s8v;
typedef __attribute__((ext_vector_type(4))) float f4v;

#define T_TOT 8
#define NSP 32768   // T*H*W
#define K_TOT 1024
#define M_TOT 1024

__device__ __forceinline__ unsigned short f2bf(float f) {
  unsigned int u = __float_as_uint(f);
  u += 0x7FFF + ((u >> 16) & 1);   // round-to-nearest-even
  return (unsigned short)(u >> 16);
}

// ---------------------------------------------------------------------------
// Kernel 1 (unchanged, ~35us, at its BW floor): depthwise 3x3x3.
// ---------------------------------------------------------------------------
__global__ __launch_bounds__(256) void dw_kernel(const float* __restrict__ X,
                                                 const float* __restrict__ DW,
                                                 unsigned short* __restrict__ Yn) {
  __shared__ float xin[8 * 18 * 64];         // 36 KB  [t][hr][w]
  const int tid = threadIdx.x;
  const int hb  = blockIdx.x;                // 0..3
  const int c   = blockIdx.y;                // 0..1023
  const int h0  = hb * 16;

  float kw[27];
#pragma unroll
  for (int j = 0; j < 27; ++j) kw[j] = DW[j];

  const float* Xc = X + (size_t)c * NSP;

#pragma unroll
  for (int i = 0; i < 9; ++i) {
    const int f  = tid + i * 256;
    const int r  = f >> 4;
    const int wq = (f & 15) * 4;
    const int t  = r / 18;
    const int hr = r - t * 18;
    const int hg = h0 - 1 + hr;
    const int hc = min(max(hg, 0), 63);
    float4 v = *(const float4*)(Xc + (t * 64 + hc) * 64 + wq);
    if (hg != hc) v = (float4){0.f, 0.f, 0.f, 0.f};
    *(float4*)&xin[r * 64 + wq] = v;
  }
  __syncthreads();

  const int w  = tid & 63;
  const int hq = tid >> 6;
  const int wl = (w == 0)  ? w : w - 1;
  const int wr = (w == 63) ? w : w + 1;
  const float* bC = &xin[(hq * 4) * 64 + w];
  const float* bL = &xin[(hq * 4) * 64 + wl];
  const float* bR = &xin[(hq * 4) * 64 + wr];
  unsigned short* Yb = Yn + (size_t)c * NSP + (h0 + hq * 4) * 64 + w;

  float a0[4], a1[4], a2[4];
#pragma unroll
  for (int j = 0; j < 4; ++j) { a0[j] = 0.f; a1[j] = 0.f; a2[j] = 0.f; }

#pragma unroll
  for (int tp = 0; tp < 8; ++tp) {
    float v[6][3];
#pragma unroll
    for (int rr = 0; rr < 6; ++rr) {
      const int off = (tp * 18 + rr) * 64;
      float xc = bC[off];
      float xl = bL[off];
      float xr = bR[off];
      if (w == 0)  xl = 0.f;
      if (w == 63) xr = 0.f;
      v[rr][0] = xl; v[rr][1] = xc; v[rr][2] = xr;
    }
#pragma unroll
    for (int j = 0; j < 4; ++j)
#pragma unroll
      for (int kh = 0; kh < 3; ++kh)
#pragma unroll
        for (int kd = 0; kd < 3; ++kd) {
          const float xv = v[j + kh][kd];
          if (tp >= 1) a0[j] += kw[(2 * 3 + kh) * 3 + kd] * xv;
          a1[j] += kw[(1 * 3 + kh) * 3 + kd] * xv;
          if (tp <= 6) a2[j] += kw[(0 * 3 + kh) * 3 + kd] * xv;
        }
    if (tp >= 1) {
      unsigned short* yp = Yb + (size_t)(tp - 1) * 4096;
#pragma unroll
      for (int j = 0; j < 4; ++j) yp[j * 64] = f2bf(a0[j]);
    }
#pragma unroll
    for (int j = 0; j < 4; ++j) { a0[j] = a1[j]; a1[j] = a2[j]; a2[j] = 0.f; }
  }
  {
    unsigned short* yp = Yb + (size_t)7 * 4096;
#pragma unroll
    for (int j = 0; j < 4; ++j) yp[j * 64] = f2bf(a0[j]);
  }
}

// ---------------------------------------------------------------------------
// Kernel 1b (unchanged, ~22us, at BW floor): transpose Yn[c][n] -> Yt[n][c].
// ---------------------------------------------------------------------------
__global__ __launch_bounds__(256) void tr_kernel(const unsigned short* __restrict__ Yn,
                                                 unsigned short* __restrict__ Yt) {
  __shared__ unsigned short tb[64][68];
  const int tid = threadIdx.x;
  const int n0  = blockIdx.x * 64;
  const int c0  = blockIdx.y * 64;

#pragma unroll
  for (int i = 0; i < 2; ++i) {
    const int cl = (tid >> 3) + i * 32;
    const int n8 = (tid & 7) * 8;
    const uint4 v = *(const uint4*)(Yn + (size_t)(c0 + cl) * NSP + n0 + n8);
    uint2 lo; lo.x = v.x; lo.y = v.y;
    uint2 hi; hi.x = v.z; hi.y = v.w;
    *(uint2*)&tb[cl][n8]     = lo;
    *(uint2*)&tb[cl][n8 + 4] = hi;
  }
  __syncthreads();

  const int nl = tid >> 2;
  const int cq = tid & 3;
#pragma unroll
  for (int i = 0; i < 2; ++i) {
    const int c8 = cq * 8 + i * 32;
    unsigned int p[4];
#pragma unroll
    for (int j = 0; j < 4; ++j) {
      const unsigned int a = tb[c8 + 2 * j][nl];
      const unsigned int b = tb[c8 + 2 * j + 1][nl];
      p[j] = a | (b << 16);
    }
    uint4 o; o.x = p[0]; o.y = p[1]; o.z = p[2]; o.w = p[3];
    *(uint4*)(Yt + (size_t)(n0 + nl) * 1024 + c0 + c8) = o;
  }
}

// ---------------------------------------------------------------------------
// Kernel 2: pointwise weight fp32 -> bf16
// ---------------------------------------------------------------------------
__global__ __launch_bounds__(256) void castw_kernel(const float* __restrict__ Wf,
                                                    unsigned short* __restrict__ Wb) {
  const int i = (blockIdx.x * 256 + threadIdx.x) * 4;
  float4 v = *(const float4*)&Wf[i];
  ushort4 o;
  o.x = f2bf(v.x); o.y = f2bf(v.y); o.z = f2bf(v.z); o.w = f2bf(v.w);
  *(ushort4*)&Wb[i] = o;
}

// ---------------------------------------------------------------------------
// Kernel 3 (v5, 8-phase template): C = A[M][K]*Bt[N][K]^T.
// BM=BN=256, BK=64, 512 threads (8 waves 2Mx4N), wave-tile 128x64 acc[8][4].
// LDS 128KB: 2 K-tile buffers x 4 half-regions [256][32] bf16 (kk0/kk1 x A/B)
// -> every region keeps the PROVEN pitch-64B both-sides swizzle (0 conflicts).
// Per K-tile 4 phases: {ds_read subtile | prefetch gloads -> s_barrier ->
// setprio(1) -> 16 MFMA (one C-quadrant, K=64) -> setprio(0) -> s_barrier}.
// All 8 prefetch loads for t+1 issue in P0/P1; single vmcnt(0) at end of P3
// (~3 phases after issue => effectively counted).  Ledger: t+1 stages write
// the buffer whose reads finished before t-1's final barrier; reads of t
// start after t-1's end-of-tile vmcnt+barrier.  Uniform control flow.
// ---------------------------------------------------------------------------
__device__ __forceinline__ void gload_lds16(const void* g, void* lds) {
  __builtin_amdgcn_global_load_lds(
      (const __attribute__((address_space(1))) void*)(uintptr_t)g,
      (__attribute__((address_space(3))) void*)(uintptr_t)lds, 16, 0, 0);
}

__global__ __launch_bounds__(512, 2) void gemm8_kernel(const unsigned short* __restrict__ A,
                                                       const unsigned short* __restrict__ B,
                                                       float* __restrict__ C) {
  __shared__ char smem[131072];              // 2 x {A0,A1,B0,B1} x 16KB
  const int tid  = threadIdx.x;
  const int lane = tid & 63;
  const int wid  = tid >> 6;
  const int wm   = wid >> 2, wn = wid & 3;   // 2 x 4 wave grid

  // bijective XCD remap: 512 wgs, 64 per XCD; bm fastest.
  const int wg = (int)blockIdx.x;
  const int lg = (wg & 7) * 64 + (wg >> 3);
  const int bm = lg & 3;                     // 0..3   (M/256)
  const int bn = lg >> 2;                    // 0..127 (N/256)

  f4v acc[8][4];
#pragma unroll
  for (int i = 0; i < 8; ++i)
#pragma unroll
    for (int j = 0; j < 4; ++j) acc[i][j] = (f4v){0.f, 0.f, 0.f, 0.f};

  const int r  = tid >> 2;                                   // 0..127
  const int kb = (((tid & 3) ^ ((tid >> 3) & 3)) * 8);       // pre-swizzled k
  const unsigned short* ga = A + (size_t)(bm * 256 + r) * K_TOT + kb;
  const unsigned short* gb = B + (size_t)(bn * 256 + r) * K_TOT + kb;
  const int stg = wid * 1024;

  // stage one [256][32] half-region: 2 gload rounds (rows 0-127 / 128-255)
#define STGH(nb, region, gptr, kof)                                          \
  do {                                                                       \
    gload_lds16((gptr) + (kof),             smem + (nb) + (region) + stg);   \
    gload_lds16((gptr) + 128 * K_TOT + (kof),                                \
                smem + (nb) + (region) + 8192 + stg);                        \
  } while (0)

  // prologue: tile 0 -> buffer 0
  STGH(0, 0,     ga, 0);
  STGH(0, 16384, ga, 32);
  STGH(0, 32768, gb, 0);
  STGH(0, 49152, gb, 32);
  asm volatile("s_waitcnt vmcnt(0)" ::: "memory");
  __builtin_amdgcn_s_barrier();

  const int cph  = ((lane >> 4) ^ ((lane >> 1) & 3)) * 8;    // swizzled col
  const int arow = wm * 128 + (lane & 15);
  const int brow = wn * 64  + (lane & 15);

  for (int t = 0; t < 16; ++t) {
    const int cu = (t & 1) << 16;
    const int nx = cu ^ 65536;
    const int kt = t * 64;
    const unsigned short* Ac = (const unsigned short*)(smem + cu);
    const unsigned short* Bc = (const unsigned short*)(smem + cu + 32768);
    const bool pf = (t < 15);
    s8v av[8], bv[8];

    // ---------------- P0: quadrant (m0-3, n0-1) ----------------
#pragma unroll
    for (int kk = 0; kk < 2; ++kk) {
#pragma unroll
      for (int nf = 0; nf < 2; ++nf)
        bv[nf * 2 + kk] = *(const s8v*)&Bc[kk * 8192 + (brow + nf * 16) * 32 + cph];
#pragma unroll
      for (int mf = 0; mf < 4; ++mf)
        av[mf * 2 + kk] = *(const s8v*)&Ac[kk * 8192 + (arow + mf * 16) * 32 + cph];
    }
    if (pf) { STGH(nx, 0, ga, kt + 64); STGH(nx, 16384, ga, kt + 96); }
    __builtin_amdgcn_s_barrier();
    __builtin_amdgcn_s_setprio(1);
#pragma unroll
    for (int mf = 0; mf < 4; ++mf)
#pragma unroll
      for (int nf = 0; nf < 2; ++nf) {
        acc[mf][nf] = __builtin_amdgcn_mfma_f32_16x16x32_bf16(av[mf*2+0], bv[nf*2+0], acc[mf][nf], 0, 0, 0);
        acc[mf][nf] = __builtin_amdgcn_mfma_f32_16x16x32_bf16(av[mf*2+1], bv[nf*2+1], acc[mf][nf], 0, 0, 0);
      }
    __builtin_amdgcn_s_setprio(0);
    __builtin_amdgcn_s_barrier();

    // ---------------- P1: quadrant (m0-3, n2-3) ----------------
#pragma unroll
    for (int kk = 0; kk < 2; ++kk)
#pragma unroll
      for (int nf = 2; nf < 4; ++nf)
        bv[nf * 2 + kk] = *(const s8v*)&Bc[kk * 8192 + (brow + nf * 16) * 32 + cph];
    if (pf) { STGH(nx, 32768, gb, kt + 64); STGH(nx, 49152, gb, kt + 96); }
    __builtin_amdgcn_s_barrier();
    __builtin_amdgcn_s_setprio(1);
#pragma unroll
    for (int mf = 0; mf < 4; ++mf)
#pragma unroll
      for (int nf = 2; nf < 4; ++nf) {
        acc[mf][nf] = __builtin_amdgcn_mfma_f32_16x16x32_bf16(av[mf*2+0], bv[nf*2+0], acc[mf][nf], 0, 0, 0);
        acc[mf][nf] = __builtin_amdgcn_mfma_f32_16x16x32_bf16(av[mf*2+1], bv[nf*2+1], acc[mf][nf], 0, 0, 0);
      }
    __builtin_amdgcn_s_setprio(0);
    __builtin_amdgcn_s_barrier();

    // ---------------- P2: quadrant (m4-7, n0-1) ----------------
#pragma unroll
    for (int kk = 0; kk < 2; ++kk)
#pragma unroll
      for (int mf = 0; mf < 4; ++mf)
        av[mf * 2 + kk] = *(const s8v*)&Ac[kk * 8192 + (arow + (mf + 4) * 16) * 32 + cph];
    __builtin_amdgcn_s_barrier();
    __builtin_amdgcn_s_setprio(1);
#pragma unroll
    for (int mf = 0; mf < 4; ++mf)
#pragma unroll
      for (int nf = 0; nf < 2; ++nf) {
        acc[mf+4][nf] = __builtin_amdgcn_mfma_f32_16x16x32_bf16(av[mf*2+0], bv[nf*2+0], acc[mf+4][nf], 0, 0, 0);
        acc[mf+4][nf] = __builtin_amdgcn_mfma_f32_16x16x32_bf16(av[mf*2+1], bv[nf*2+1], acc[mf+4][nf], 0, 0, 0);
      }
    __builtin_amdgcn_s_setprio(0);
    __builtin_amdgcn_s_barrier();

    // ---------------- P3: quadrant (m4-7, n2-3) ----------------
    __builtin_amdgcn_s_setprio(1);
#pragma unroll
    for (int mf = 0; mf < 4; ++mf)
#pragma unroll
      for (int nf = 2; nf < 4; ++nf) {
        acc[mf+4][nf] = __builtin_amdgcn_mfma_f32_16x16x32_bf16(av[mf*2+0], bv[nf*2+0], acc[mf+4][nf], 0, 0, 0);
        acc[mf+4][nf] = __builtin_amdgcn_mfma_f32_16x16x32_bf16(av[mf*2+1], bv[nf*2+1], acc[mf+4][nf], 0, 0, 0);
      }
    __builtin_amdgcn_s_setprio(0);
    if (pf) asm volatile("s_waitcnt vmcnt(0)" ::: "memory");
    __builtin_amdgcn_s_barrier();
  }
#undef STGH

  const int rowq = (lane >> 4) * 4;
  const int colq = lane & 15;
#pragma unroll
  for (int mf = 0; mf < 8; ++mf) {
    const int row0 = bm * 256 + wm * 128 + mf * 16 + rowq;
#pragma unroll
    for (int nf = 0; nf < 4; ++nf) {
      const int col = bn * 256 + wn * 64 + nf * 16 + colq;
      float* cp = C + (size_t)row0 * NSP + col;
#pragma unroll
      for (int j = 0; j < 4; ++j) cp[(size_t)j * NSP] = acc[mf][nf][j];
    }
  }
}

// ---------------------------------------------------------------------------
// Fallback GEMM (round-3 verbatim): used only if ws can't fit Yn+Yt.
// ---------------------------------------------------------------------------
__global__ __launch_bounds__(256) void gemm_nmajor_kernel(const unsigned short* __restrict__ A,
                                                          const unsigned short* __restrict__ B,
                                                          float* __restrict__ C) {
  __shared__ unsigned short As[128][32];
  __shared__ unsigned short Bs[128][40];
  const int tid  = threadIdx.x;
  const int lane = tid & 63;
  const int wv   = tid >> 6;
  const int wr   = wv >> 1, wc = wv & 1;
  const int bn   = blockIdx.x, bm = blockIdx.y;
  const int n0   = bn * 128;

  f4v acc[4][4];
#pragma unroll
  for (int i = 0; i < 4; ++i)
#pragma unroll
    for (int j = 0; j < 4; ++j) acc[i][j] = (f4v){0.f, 0.f, 0.f, 0.f};

  const int r  = tid >> 2;
  const int kb = (tid & 3) * 8;
  const unsigned short* ga0 = A + (size_t)(bm * 128 + r) * K_TOT + kb;
  char* ldsA = (char*)(&As[0][0]) + wv * 1024;
  const int nq4 = (tid >> 3) * 4;
  const int kq4 = (tid & 7) * 4;

  for (int kt = 0; kt < K_TOT; kt += 32) {
    __syncthreads();
    gload_lds16(ga0 + kt,               ldsA);
    gload_lds16(ga0 + 64 * K_TOT + kt,  ldsA + 4096);

    const unsigned short* gB = B + (size_t)(kt + kq4) * NSP + n0 + nq4;
    uint2 L0 = *(const uint2*)(gB);
    uint2 L1 = *(const uint2*)(gB + NSP);
    uint2 L2 = *(const uint2*)(gB + 2 * NSP);
    uint2 L3 = *(const uint2*)(gB + 3 * NSP);
    uint2 W0, W1, W2, W3;
    W0.x = (L0.x & 0xFFFFu) | (L1.x << 16);
    W0.y = (L2.x & 0xFFFFu) | (L3.x << 16);
    W1.x = (L0.x >> 16) | (L1.x & 0xFFFF0000u);
    W1.y = (L2.x >> 16) | (L3.x & 0xFFFF0000u);
    W2.x = (L0.y & 0xFFFFu) | (L1.y << 16);
    W2.y = (L2.y & 0xFFFFu) | (L3.y << 16);
    W3.x = (L0.y >> 16) | (L1.y & 0xFFFF0000u);
    W3.y = (L2.y >> 16) | (L3.y & 0xFFFF0000u);
    *(uint2*)&Bs[nq4 + 0][kq4] = W0;
    *(uint2*)&Bs[nq4 + 1][kq4] = W1;
    *(uint2*)&Bs[nq4 + 2][kq4] = W2;
    *(uint2*)&Bs[nq4 + 3][kq4] = W3;
    __syncthreads();

    s8v a[4], b[4];
#pragma unroll
    for (int mf = 0; mf < 4; ++mf)
      a[mf] = *(const s8v*)&As[wr * 64 + mf * 16 + (lane & 15)][(lane >> 4) * 8];
#pragma unroll
    for (int nf = 0; nf < 4; ++nf)
      b[nf] = *(const s8v*)&Bs[wc * 64 + nf * 16 + (lane & 15)][(lane >> 4) * 8];
#pragma unroll
    for (int mf = 0; mf < 4; ++mf)
#pragma unroll
      for (int nf = 0; nf < 4; ++nf)
        acc[mf][nf] = __builtin_amdgcn_mfma_f32_16x16x32_bf16(a[mf], b[nf], acc[mf][nf], 0, 0, 0);
  }

  const int rowq = (lane >> 4) * 4;
  const int colq = lane & 15;
#pragma unroll
  for (int mf = 0; mf < 4; ++mf) {
    const int row0 = bm * 128 + wr * 64 + mf * 16 + rowq;
#pragma unroll
    for (int nf = 0; nf < 4; ++nf) {
      const int col = n0 + wc * 64 + nf * 16 + colq;
      float* cp = C + (size_t)row0 * NSP + col;
#pragma unroll
      for (int j = 0; j < 4; ++j) cp[(size_t)j * NSP] = acc[mf][nf][j];
    }
  }
}

// ---------------------------------------------------------------------------
extern "C" void kernel_launch(void* const* d_in, const int* in_sizes, int n_in,
                              void* d_out, int out_size, void* d_ws, size_t ws_size,
                              hipStream_t stream) {
  const float* feat = (const float*)d_in[0];
  const float* dw   = (const float*)d_in[1];
  const float* pw   = (const float*)d_in[2];
  float* out = (float*)d_out;

  const size_t YBYTES = (size_t)K_TOT * NSP * 2;   // 64 MiB

  if (ws_size >= 2 * YBYTES) {
    unsigned short* Yt = (unsigned short*)d_ws;
    unsigned short* Yn = (unsigned short*)((char*)d_ws + YBYTES);
    unsigned short* Wb = Yn;                       // reused after tr_kernel
    dw_kernel<<<dim3(4, 1024), dim3(256), 0, stream>>>(feat, dw, Yn);
    tr_kernel<<<dim3(512, 16), dim3(256), 0, stream>>>(Yn, Yt);
    castw_kernel<<<dim3(1024), dim3(256), 0, stream>>>(pw, Wb);
    gemm8_kernel<<<dim3(512), dim3(512), 0, stream>>>(Wb, Yt, out);
  } else {
    unsigned short* Yn = (unsigned short*)d_ws;
    unsigned short* Wb = Yn + (size_t)K_TOT * NSP;
    dw_kernel<<<dim3(4, 1024), dim3(256), 0, stream>>>(feat, dw, Yn);
    castw_kernel<<<dim3(1024), dim3(256), 0, stream>>>(pw, Wb);
    gemm_nmajor_kernel<<<dim3(256, 8), dim3(256), 0, stream>>>(Wb, Yn, out);
  }
}

// Round 9
// 151.910 us; speedup vs baseline: 3.2822x; 1.0152x over previous
//
#include <hip/hip_runtime.h>
#include <hip/hip_bf16.h>
#include <stdint.h>

typedef __attribute__((ext_vector_type(8))) short s8v;
typedef __attribute__((ext_vector_type(4))) float f4v;

#define T_TOT 8
#define NSP 32768   // T*H*W
#define K_TOT 1024
#define M_TOT 1024

__device__ __forceinline__ unsigned short f2bf(float f) {
  unsigned int u = __float_as_uint(f);
  u += 0x7FFF + ((u >> 16) & 1);   // round-to-nearest-even
  return (unsigned short)(u >> 16);
}

// ---------------------------------------------------------------------------
// Kernel 1 (unchanged, ~35us, at its BW floor): depthwise 3x3x3.
// ---------------------------------------------------------------------------
__global__ __launch_bounds__(256) void dw_kernel(const float* __restrict__ X,
                                                 const float* __restrict__ DW,
                                                 unsigned short* __restrict__ Yn) {
  __shared__ float xin[8 * 18 * 64];         // 36 KB  [t][hr][w]
  const int tid = threadIdx.x;
  const int hb  = blockIdx.x;                // 0..3
  const int c   = blockIdx.y;                // 0..1023
  const int h0  = hb * 16;

  float kw[27];
#pragma unroll
  for (int j = 0; j < 27; ++j) kw[j] = DW[j];

  const float* Xc = X + (size_t)c * NSP;

#pragma unroll
  for (int i = 0; i < 9; ++i) {
    const int f  = tid + i * 256;
    const int r  = f >> 4;
    const int wq = (f & 15) * 4;
    const int t  = r / 18;
    const int hr = r - t * 18;
    const int hg = h0 - 1 + hr;
    const int hc = min(max(hg, 0), 63);
    float4 v = *(const float4*)(Xc + (t * 64 + hc) * 64 + wq);
    if (hg != hc) v = (float4){0.f, 0.f, 0.f, 0.f};
    *(float4*)&xin[r * 64 + wq] = v;
  }
  __syncthreads();

  const int w  = tid & 63;
  const int hq = tid >> 6;
  const int wl = (w == 0)  ? w : w - 1;
  const int wr = (w == 63) ? w : w + 1;
  const float* bC = &xin[(hq * 4) * 64 + w];
  const float* bL = &xin[(hq * 4) * 64 + wl];
  const float* bR = &xin[(hq * 4) * 64 + wr];
  unsigned short* Yb = Yn + (size_t)c * NSP + (h0 + hq * 4) * 64 + w;

  float a0[4], a1[4], a2[4];
#pragma unroll
  for (int j = 0; j < 4; ++j) { a0[j] = 0.f; a1[j] = 0.f; a2[j] = 0.f; }

#pragma unroll
  for (int tp = 0; tp < 8; ++tp) {
    float v[6][3];
#pragma unroll
    for (int rr = 0; rr < 6; ++rr) {
      const int off = (tp * 18 + rr) * 64;
      float xc = bC[off];
      float xl = bL[off];
      float xr = bR[off];
      if (w == 0)  xl = 0.f;
      if (w == 63) xr = 0.f;
      v[rr][0] = xl; v[rr][1] = xc; v[rr][2] = xr;
    }
#pragma unroll
    for (int j = 0; j < 4; ++j)
#pragma unroll
      for (int kh = 0; kh < 3; ++kh)
#pragma unroll
        for (int kd = 0; kd < 3; ++kd) {
          const float xv = v[j + kh][kd];
          if (tp >= 1) a0[j] += kw[(2 * 3 + kh) * 3 + kd] * xv;
          a1[j] += kw[(1 * 3 + kh) * 3 + kd] * xv;
          if (tp <= 6) a2[j] += kw[(0 * 3 + kh) * 3 + kd] * xv;
        }
    if (tp >= 1) {
      unsigned short* yp = Yb + (size_t)(tp - 1) * 4096;
#pragma unroll
      for (int j = 0; j < 4; ++j) yp[j * 64] = f2bf(a0[j]);
    }
#pragma unroll
    for (int j = 0; j < 4; ++j) { a0[j] = a1[j]; a1[j] = a2[j]; a2[j] = 0.f; }
  }
  {
    unsigned short* yp = Yb + (size_t)7 * 4096;
#pragma unroll
    for (int j = 0; j < 4; ++j) yp[j * 64] = f2bf(a0[j]);
  }
}

// ---------------------------------------------------------------------------
// Kernel 1b (unchanged, ~22us, at BW floor): transpose Yn[c][n] -> Yt[n][c].
// ---------------------------------------------------------------------------
__global__ __launch_bounds__(256) void tr_kernel(const unsigned short* __restrict__ Yn,
                                                 unsigned short* __restrict__ Yt) {
  __shared__ unsigned short tb[64][68];
  const int tid = threadIdx.x;
  const int n0  = blockIdx.x * 64;
  const int c0  = blockIdx.y * 64;

#pragma unroll
  for (int i = 0; i < 2; ++i) {
    const int cl = (tid >> 3) + i * 32;
    const int n8 = (tid & 7) * 8;
    const uint4 v = *(const uint4*)(Yn + (size_t)(c0 + cl) * NSP + n0 + n8);
    uint2 lo; lo.x = v.x; lo.y = v.y;
    uint2 hi; hi.x = v.z; hi.y = v.w;
    *(uint2*)&tb[cl][n8]     = lo;
    *(uint2*)&tb[cl][n8 + 4] = hi;
  }
  __syncthreads();

  const int nl = tid >> 2;
  const int cq = tid & 3;
#pragma unroll
  for (int i = 0; i < 2; ++i) {
    const int c8 = cq * 8 + i * 32;
    unsigned int p[4];
#pragma unroll
    for (int j = 0; j < 4; ++j) {
      const unsigned int a = tb[c8 + 2 * j][nl];
      const unsigned int b = tb[c8 + 2 * j + 1][nl];
      p[j] = a | (b << 16);
    }
    uint4 o; o.x = p[0]; o.y = p[1]; o.z = p[2]; o.w = p[3];
    *(uint4*)(Yt + (size_t)(n0 + nl) * 1024 + c0 + c8) = o;
  }
}

// ---------------------------------------------------------------------------
// Kernel 2: pointwise weight fp32 -> bf16
// ---------------------------------------------------------------------------
__global__ __launch_bounds__(256) void castw_kernel(const float* __restrict__ Wf,
                                                    unsigned short* __restrict__ Wb) {
  const int i = (blockIdx.x * 256 + threadIdx.x) * 4;
  float4 v = *(const float4*)&Wf[i];
  ushort4 o;
  o.x = f2bf(v.x); o.y = f2bf(v.y); o.z = f2bf(v.z); o.w = f2bf(v.w);
  *(ushort4*)&Wb[i] = o;
}

// ---------------------------------------------------------------------------
// Kernel 3 (v6, kk-split counted pipeline): C = A[M][K]*Bt[N][K]^T.
// BM=BN=256, BK=64, 512 thr (8 waves 2Mx4N), wave-tile 128x64, acc[8][4].
// LDS 128KB = 2 buffers x {A-kk0,A-kk1,B-kk0,B-kk1} x 16KB ([256][32],
// proven both-sides swizzle, 0 conflicts).
// Phases are K-halves (not C-quadrants): P(t,kk) reads ONLY the kk regions
// (12 ds_read_b128) and runs all 32 MFMAs for that kk.  Needs are therefore
// phase-ordered in K => true counted pipeline with 2 buffers:
//   stage t+1.kk issued inside P(t,kk); EVERY boundary = vmcnt(4)+s_barrier
//   (oldest 4 = half needed now; newest 4 stay in flight). Never drains in
//   steady state; single vmcnt(0) before the last tile.  Barriers: 2/K-tile
//   (was 8).  WAR ledger: stage into buf[nx] is >=2 barriers after that
//   buffer's last reads.
// ---------------------------------------------------------------------------
__device__ __forceinline__ void gload_lds16(const void* g, void* lds) {
  __builtin_amdgcn_global_load_lds(
      (const __attribute__((address_space(1))) void*)(uintptr_t)g,
      (__attribute__((address_space(3))) void*)(uintptr_t)lds, 16, 0, 0);
}

__global__ __launch_bounds__(512, 2) void gemm8_kernel(const unsigned short* __restrict__ A,
                                                       const unsigned short* __restrict__ B,
                                                       float* __restrict__ C) {
  __shared__ char smem[131072];              // 2 x {A0,A1,B0,B1} x 16KB
  const int tid  = threadIdx.x;
  const int lane = tid & 63;
  const int wid  = tid >> 6;
  const int wm   = wid >> 2, wn = wid & 3;   // 2 x 4 wave grid

  // bijective XCD remap: 512 wgs, 64 per XCD; bm fastest.
  const int wg = (int)blockIdx.x;
  const int lg = (wg & 7) * 64 + (wg >> 3);
  const int bm = lg & 3;                     // 0..3   (M/256)
  const int bn = lg >> 2;                    // 0..127 (N/256)

  f4v acc[8][4];
#pragma unroll
  for (int i = 0; i < 8; ++i)
#pragma unroll
    for (int j = 0; j < 4; ++j) acc[i][j] = (f4v){0.f, 0.f, 0.f, 0.f};

  const int r  = tid >> 2;                                   // 0..127
  const int kb = (((tid & 3) ^ ((tid >> 3) & 3)) * 8);       // pre-swizzled k
  const unsigned short* ga = A + (size_t)(bm * 256 + r) * K_TOT + kb;
  const unsigned short* gb = B + (size_t)(bn * 256 + r) * K_TOT + kb;
  const int stg = wid * 1024;

  // stage one kk-half of tile tt into buffer nb: A region + B region, 4 loads
#define STAGE_KK(nb, tt, kk)                                                  \
  do {                                                                        \
    const int ko = (tt) * 64 + (kk) * 32;                                     \
    char* ab = smem + (nb) + (kk) * 16384 + stg;                              \
    char* bb = smem + (nb) + 32768 + (kk) * 16384 + stg;                      \
    gload_lds16(ga + ko,                 ab);                                 \
    gload_lds16(ga + 128 * K_TOT + ko,   ab + 8192);                          \
    gload_lds16(gb + ko,                 bb);                                 \
    gload_lds16(gb + 128 * K_TOT + ko,   bb + 8192);                          \
  } while (0)

  const int cph  = ((lane >> 4) ^ ((lane >> 1) & 3)) * 8;    // swizzled col
  const int arow = wm * 128 + (lane & 15);
  const int brow = wn * 64  + (lane & 15);

  // one phase: read kk regions of buffer cu, optionally stage t+1's kk half
  // into nx, then 32 MFMAs for this kk.
#define PHASE(cu, nx, tt, kk, pf)                                             \
  do {                                                                        \
    const unsigned short* Ac = (const unsigned short*)(smem + (cu));          \
    const unsigned short* Bc = (const unsigned short*)(smem + (cu) + 32768);  \
    s8v av[8], bv[4];                                                         \
    _Pragma("unroll")                                                         \
    for (int nf = 0; nf < 4; ++nf)                                            \
      bv[nf] = *(const s8v*)&Bc[(kk) * 8192 + (brow + nf * 16) * 32 + cph];   \
    _Pragma("unroll")                                                         \
    for (int mf = 0; mf < 8; ++mf)                                            \
      av[mf] = *(const s8v*)&Ac[(kk) * 8192 + (arow + mf * 16) * 32 + cph];   \
    if (pf) STAGE_KK(nx, (tt) + 1, kk);                                       \
    __builtin_amdgcn_s_setprio(1);                                            \
    _Pragma("unroll")                                                         \
    for (int mf = 0; mf < 8; ++mf)                                            \
      _Pragma("unroll")                                                       \
      for (int nf = 0; nf < 4; ++nf)                                          \
        acc[mf][nf] = __builtin_amdgcn_mfma_f32_16x16x32_bf16(                \
            av[mf], bv[nf], acc[mf][nf], 0, 0, 0);                            \
    __builtin_amdgcn_s_setprio(0);                                            \
  } while (0)

  // prologue: tile 0 both halves in flight (8 loads)
  STAGE_KK(0, 0, 0);
  STAGE_KK(0, 0, 1);

  for (int t = 0; t < 15; ++t) {
    const int cu = (t & 1) << 16;
    const int nx = cu ^ 65536;
    asm volatile("s_waitcnt vmcnt(4)" ::: "memory");   // t.kk0 landed; t.kk1 may fly
    __builtin_amdgcn_s_barrier();
    PHASE(cu, nx, t, 0, true);                         // issues t+1.kk0
    asm volatile("s_waitcnt vmcnt(4)" ::: "memory");   // t.kk1 landed; t+1.kk0 may fly
    __builtin_amdgcn_s_barrier();
    PHASE(cu, nx, t, 1, true);                         // issues t+1.kk1
  }
  // tail: tile 15 (buffer 1), nothing left to prefetch
  asm volatile("s_waitcnt vmcnt(0)" ::: "memory");
  __builtin_amdgcn_s_barrier();
  PHASE(65536, 0, 15, 0, false);
  PHASE(65536, 0, 15, 1, false);

#undef PHASE
#undef STAGE_KK

  const int rowq = (lane >> 4) * 4;
  const int colq = lane & 15;
#pragma unroll
  for (int mf = 0; mf < 8; ++mf) {
    const int row0 = bm * 256 + wm * 128 + mf * 16 + rowq;
#pragma unroll
    for (int nf = 0; nf < 4; ++nf) {
      const int col = bn * 256 + wn * 64 + nf * 16 + colq;
      float* cp = C + (size_t)row0 * NSP + col;
#pragma unroll
      for (int j = 0; j < 4; ++j) cp[(size_t)j * NSP] = acc[mf][nf][j];
    }
  }
}

// ---------------------------------------------------------------------------
// Fallback GEMM (round-3 verbatim): used only if ws can't fit Yn+Yt.
// ---------------------------------------------------------------------------
__global__ __launch_bounds__(256) void gemm_nmajor_kernel(const unsigned short* __restrict__ A,
                                                          const unsigned short* __restrict__ B,
                                                          float* __restrict__ C) {
  __shared__ unsigned short As[128][32];
  __shared__ unsigned short Bs[128][40];
  const int tid  = threadIdx.x;
  const int lane = tid & 63;
  const int wv   = tid >> 6;
  const int wr   = wv >> 1, wc = wv & 1;
  const int bn   = blockIdx.x, bm = blockIdx.y;
  const int n0   = bn * 128;

  f4v acc[4][4];
#pragma unroll
  for (int i = 0; i < 4; ++i)
#pragma unroll
    for (int j = 0; j < 4; ++j) acc[i][j] = (f4v){0.f, 0.f, 0.f, 0.f};

  const int r  = tid >> 2;
  const int kb = (tid & 3) * 8;
  const unsigned short* ga0 = A + (size_t)(bm * 128 + r) * K_TOT + kb;
  char* ldsA = (char*)(&As[0][0]) + wv * 1024;
  const int nq4 = (tid >> 3) * 4;
  const int kq4 = (tid & 7) * 4;

  for (int kt = 0; kt < K_TOT; kt += 32) {
    __syncthreads();
    gload_lds16(ga0 + kt,               ldsA);
    gload_lds16(ga0 + 64 * K_TOT + kt,  ldsA + 4096);

    const unsigned short* gB = B + (size_t)(kt + kq4) * NSP + n0 + nq4;
    uint2 L0 = *(const uint2*)(gB);
    uint2 L1 = *(const uint2*)(gB + NSP);
    uint2 L2 = *(const uint2*)(gB + 2 * NSP);
    uint2 L3 = *(const uint2*)(gB + 3 * NSP);
    uint2 W0, W1, W2, W3;
    W0.x = (L0.x & 0xFFFFu) | (L1.x << 16);
    W0.y = (L2.x & 0xFFFFu) | (L3.x << 16);
    W1.x = (L0.x >> 16) | (L1.x & 0xFFFF0000u);
    W1.y = (L2.x >> 16) | (L3.x & 0xFFFF0000u);
    W2.x = (L0.y & 0xFFFFu) | (L1.y << 16);
    W2.y = (L2.y & 0xFFFFu) | (L3.y << 16);
    W3.x = (L0.y >> 16) | (L1.y & 0xFFFF0000u);
    W3.y = (L2.y >> 16) | (L3.y & 0xFFFF0000u);
    *(uint2*)&Bs[nq4 + 0][kq4] = W0;
    *(uint2*)&Bs[nq4 + 1][kq4] = W1;
    *(uint2*)&Bs[nq4 + 2][kq4] = W2;
    *(uint2*)&Bs[nq4 + 3][kq4] = W3;
    __syncthreads();

    s8v a[4], b[4];
#pragma unroll
    for (int mf = 0; mf < 4; ++mf)
      a[mf] = *(const s8v*)&As[wr * 64 + mf * 16 + (lane & 15)][(lane >> 4) * 8];
#pragma unroll
    for (int nf = 0; nf < 4; ++nf)
      b[nf] = *(const s8v*)&Bs[wc * 64 + nf * 16 + (lane & 15)][(lane >> 4) * 8];
#pragma unroll
    for (int mf = 0; mf < 4; ++mf)
#pragma unroll
      for (int nf = 0; nf < 4; ++nf)
        acc[mf][nf] = __builtin_amdgcn_mfma_f32_16x16x32_bf16(a[mf], b[nf], acc[mf][nf], 0, 0, 0);
  }

  const int rowq = (lane >> 4) * 4;
  const int colq = lane & 15;
#pragma unroll
  for (int mf = 0; mf < 4; ++mf) {
    const int row0 = bm * 128 + wr * 64 + mf * 16 + rowq;
#pragma unroll
    for (int nf = 0; nf < 4; ++nf) {
      const int col = n0 + wc * 64 + nf * 16 + colq;
      float* cp = C + (size_t)row0 * NSP + col;
#pragma unroll
      for (int j = 0; j < 4; ++j) cp[(size_t)j * NSP] = acc[mf][nf][j];
    }
  }
}

// ---------------------------------------------------------------------------
extern "C" void kernel_launch(void* const* d_in, const int* in_sizes, int n_in,
                              void* d_out, int out_size, void* d_ws, size_t ws_size,
                              hipStream_t stream) {
  const float* feat = (const float*)d_in[0];
  const float* dw   = (const float*)d_in[1];
  const float* pw   = (const float*)d_in[2];
  float* out = (float*)d_out;

  const size_t YBYTES = (size_t)K_TOT * NSP * 2;   // 64 MiB

  if (ws_size >= 2 * YBYTES) {
    unsigned short* Yt = (unsigned short*)d_ws;
    unsigned short* Yn = (unsigned short*)((char*)d_ws + YBYTES);
    unsigned short* Wb = Yn;                       // reused after tr_kernel
    dw_kernel<<<dim3(4, 1024), dim3(256), 0, stream>>>(feat, dw, Yn);
    tr_kernel<<<dim3(512, 16), dim3(256), 0, stream>>>(Yn, Yt);
    castw_kernel<<<dim3(1024), dim3(256), 0, stream>>>(pw, Wb);
    gemm8_kernel<<<dim3(512), dim3(512), 0, stream>>>(Wb, Yt, out);
  } else {
    unsigned short* Yn = (unsigned short*)d_ws;
    unsigned short* Wb = Yn + (size_t)K_TOT * NSP;
    dw_kernel<<<dim3(4, 1024), dim3(256), 0, stream>>>(feat, dw, Yn);
    castw_kernel<<<dim3(1024), dim3(256), 0, stream>>>(pw, Wb);
    gemm_nmajor_kernel<<<dim3(256, 8), dim3(256), 0, stream>>>(Wb, Yn, out);
  }
}